// Round 1
// baseline (8633.619 us; speedup 1.0000x reference)
//
#include <hip/hip_runtime.h>
#include <stdint.h>

#define N_TOK 2048
#define IN_D  1024
#define OUT_D 10
#define NEXP  10
#define MMEM  24
#define NSTEP 4
#define NDST  40
#define INNER 768
#define SHD   2048
#define DMAX  3328
#define DSUM  24064

typedef __attribute__((ext_vector_type(4))) float f32x4;
typedef __attribute__((ext_vector_type(8))) short bf16x8;

__device__ const int c_dims[10] = {1536,2048,2560,3072,1792,2304,2816,2048,2560,3328};
__device__ const int c_offs[10] = {0,1536,3584,6144,9216,11008,13312,16128,18176,20736};
__device__ const int c_acts[10] = {0,1,2,3,4,5,6,7,0,1};

__device__ __forceinline__ float wred(float v){
#pragma unroll
  for (int s = 32; s > 0; s >>= 1) v += __shfl_xor(v, s, 64);
  return v;
}

__device__ __forceinline__ float bf2f(uint16_t u){
  return __uint_as_float(((uint32_t)u) << 16);
}
__device__ __forceinline__ uint16_t f2bf(float f){
  uint32_t u = __float_as_uint(f);
  return (uint16_t)((u + 0x7FFFu + ((u >> 16) & 1u)) >> 16);
}

__device__ __forceinline__ float actf(int a, float x){
  switch(a){
    case 0: return x / (1.f + expf(-x));                               // silu
    case 1: return 0.5f * x * (1.f + erff(x * 0.7071067811865475f));   // gelu exact
    case 2: { float sp = fmaxf(x,0.f) + log1pf(expf(-fabsf(x)));       // mish
              return x * tanhf(sp); }
    case 3: return fmaxf(x, 0.f);                                      // relu
    case 4: return x > 0.f ? 1.0507009873554805f * x                   // selu
                           : 1.7580993408473768f * expm1f(x);
    case 5: return tanhf(x);                                           // tanh
    case 6: return fmaxf(x,0.f) + log1pf(expf(-fabsf(x)));             // softplus
    default: return x > 0.f ? x : expm1f(x);                           // elu
  }
}

// ---------------- generic f32 tiled GEMM: C[n,d] = epi(sum_k A[n,k]*W[d,k]) ----
enum { EPI_NONE=0, EPI_BIAS=1, EPI_GELU_BIAS=2, EPI_ADD_BIAS=3, EPI_SILU=4 };

template<int EPI>
__global__ __launch_bounds__(256)
void gemm_f32(const float* __restrict__ A, const float* __restrict__ W,
              const float* __restrict__ bias, const float* __restrict__ addend,
              float* __restrict__ C, int K, int D)
{
  __shared__ __align__(16) float As[16][64];
  __shared__ __align__(16) float Ws[16][64];
  int tid = threadIdx.x;
  int rowBase = blockIdx.y * 64, colBase = blockIdx.x * 64;
  int tx = tid & 15, ty = tid >> 4;
  float acc[4][4] = {};
  int r = tid >> 2, c4 = (tid & 3) << 2;
  const float* Arow = A + (size_t)(rowBase + r) * K + c4;
  const float* Wrow = W + (size_t)(colBase + r) * K + c4;
  for (int k0 = 0; k0 < K; k0 += 16){
    float4 av = *(const float4*)(Arow + k0);
    float4 wv = *(const float4*)(Wrow + k0);
    As[c4+0][r]=av.x; As[c4+1][r]=av.y; As[c4+2][r]=av.z; As[c4+3][r]=av.w;
    Ws[c4+0][r]=wv.x; Ws[c4+1][r]=wv.y; Ws[c4+2][r]=wv.z; Ws[c4+3][r]=wv.w;
    __syncthreads();
#pragma unroll
    for (int kk = 0; kk < 16; kk++){
      float4 a = *(const float4*)&As[kk][ty << 2];
      float4 b = *(const float4*)&Ws[kk][tx << 2];
      float aa[4] = {a.x,a.y,a.z,a.w}, bb[4] = {b.x,b.y,b.z,b.w};
#pragma unroll
      for (int i = 0; i < 4; i++)
#pragma unroll
        for (int j = 0; j < 4; j++) acc[i][j] = fmaf(aa[i], bb[j], acc[i][j]);
    }
    __syncthreads();
  }
#pragma unroll
  for (int i = 0; i < 4; i++){
    int row = rowBase + (ty << 2) + i;
#pragma unroll
    for (int j = 0; j < 4; j++){
      int col = colBase + (tx << 2) + j;
      float v = acc[i][j];
      if (EPI == EPI_BIAS || EPI == EPI_GELU_BIAS || EPI == EPI_ADD_BIAS) v += bias[col];
      if (EPI == EPI_GELU_BIAS) v = 0.5f * v * (1.f + erff(v * 0.7071067811865475f));
      if (EPI == EPI_SILU)      v = v / (1.f + expf(-v));
      if (EPI == EPI_ADD_BIAS)  v += addend[(size_t)row * D + col];
      C[(size_t)row * D + col] = v;
    }
  }
}

// ---------------- expert up-projection, bf16 MFMA 16x16x32, 128x128 tile ------
__global__ __launch_bounds__(256)
void expert_up_mfma(const uint16_t* __restrict__ Abf, const uint16_t* __restrict__ Ubf,
                    uint16_t* __restrict__ HH)
{
  int e = blockIdx.z;
  int dcols = c_dims[e];
  int ct = blockIdx.y;
  if (ct * 128 >= dcols) return;
  const uint16_t* W = Ubf + (size_t)e * DMAX * IN_D + (size_t)ct * 128 * IN_D;
  int rowBase = blockIdx.x * 128;
  __shared__ __align__(16) uint16_t As[128 * 32];
  __shared__ __align__(16) uint16_t Bs[128 * 32];
  int tid = threadIdx.x, lane = tid & 63, wave = tid >> 6;
  int wr = wave >> 1, wc = wave & 1;
  int arow = lane & 15, agrp = lane >> 4;
  f32x4 acc[4][4];
#pragma unroll
  for (int m = 0; m < 4; m++)
#pragma unroll
    for (int n = 0; n < 4; n++){ f32x4 z = {0.f,0.f,0.f,0.f}; acc[m][n] = z; }

  for (int k0 = 0; k0 < IN_D; k0 += 32){
#pragma unroll
    for (int s = 0; s < 2; s++){
      int c = tid + s * 256;
      int rr = c >> 2, cc = (c & 3) << 3;
      *(int4*)&As[c << 3] = *(const int4*)&Abf[(size_t)(rowBase + rr) * IN_D + k0 + cc];
      *(int4*)&Bs[c << 3] = *(const int4*)&W[(size_t)rr * IN_D + k0 + cc];
    }
    __syncthreads();
    bf16x8 a[4], b[4];
#pragma unroll
    for (int m = 0; m < 4; m++) a[m] = *(const bf16x8*)&As[(wr*64 + m*16 + arow) * 32 + agrp * 8];
#pragma unroll
    for (int n = 0; n < 4; n++) b[n] = *(const bf16x8*)&Bs[(wc*64 + n*16 + arow) * 32 + agrp * 8];
#pragma unroll
    for (int m = 0; m < 4; m++)
#pragma unroll
      for (int n = 0; n < 4; n++)
        acc[m][n] = __builtin_amdgcn_mfma_f32_16x16x32_bf16(a[m], b[n], acc[m][n], 0, 0, 0);
    __syncthreads();
  }
  int actid = c_acts[e];
  size_t colG0 = (size_t)c_offs[e] + ct * 128 + wc * 64 + (lane & 15);
#pragma unroll
  for (int m = 0; m < 4; m++){
#pragma unroll
    for (int n = 0; n < 4; n++){
#pragma unroll
      for (int r2 = 0; r2 < 4; r2++){
        int row = rowBase + wr * 64 + m * 16 + (lane >> 4) * 4 + r2;
        float v = actf(actid, acc[m][n][r2]);
        HH[(size_t)row * DSUM + colG0 + n * 16] = f2bf(v);
      }
    }
  }
}

// ---------------- expert down-proj + LN + gated accumulate (skip gate==0) ------
__global__ __launch_bounds__(256)
void expert_down(const uint16_t* __restrict__ HH, const float* __restrict__ ED,
                 const float* __restrict__ sg, const float* __restrict__ eng,
                 const float* __restrict__ enb, float* __restrict__ EL)
{
  int lane = threadIdx.x & 63;
  int row = blockIdx.x * 4 + (threadIdx.x >> 6);
  float out[10] = {};
  for (int e = 0; e < NEXP; e++){
    float g = sg[row * 10 + e];
    if (g != 0.0f){
      int d = c_dims[e];
      const uint16_t* hr = HH + (size_t)row * DSUM + c_offs[e];
      const float* wd = ED + (size_t)e * 10 * DMAX;
      float p[10] = {};
      for (int k = lane; k < d; k += 64){
        float hv = bf2f(hr[k]);
#pragma unroll
        for (int o = 0; o < 10; o++) p[o] = fmaf(hv, wd[o * DMAX + k], p[o]);
      }
#pragma unroll
      for (int o = 0; o < 10; o++) p[o] = wred(p[o]);
      float mean = 0.f;
#pragma unroll
      for (int o = 0; o < 10; o++) mean += p[o];
      mean *= 0.1f;
      float var = 0.f;
#pragma unroll
      for (int o = 0; o < 10; o++){ float dd = p[o] - mean; var += dd * dd; }
      var *= 0.1f;
      float rs = 1.f / sqrtf(var + 1e-5f);
#pragma unroll
      for (int o = 0; o < 10; o++)
        out[o] += g * ((p[o] - mean) * rs * eng[e * 10 + o] + enb[e * 10 + o]);
    }
  }
  if (lane == 0){
#pragma unroll
    for (int o = 0; o < 10; o++) EL[row * 10 + o] = out[o];
  }
}

// ---------------- memory attention: softmax(mq@keys^T/32) -> u, s_tau ---------
__global__ __launch_bounds__(256)
void mem_attn_kernel(const float* __restrict__ mq, const float* __restrict__ keys,
                     const float* __restrict__ Ac, const float* __restrict__ W0,
                     const float* __restrict__ W1, const float* __restrict__ W2,
                     float* __restrict__ ubuf, float* __restrict__ sval, int t)
{
  int lane = threadIdx.x & 63;
  int row = blockIdx.x * 4 + (threadIdx.x >> 6);
  size_t rb = (size_t)row * IN_D;
  float p[24];
#pragma unroll
  for (int m = 0; m < 24; m++) p[m] = 0.f;
  for (int k = lane; k < IN_D; k += 64){
    float qv = mq[rb + k];
#pragma unroll
    for (int m = 0; m < 24; m++) p[m] = fmaf(qv, keys[m * IN_D + k], p[m]);
  }
#pragma unroll
  for (int m = 0; m < 24; m++) p[m] = wred(p[m]) * 0.03125f;
  float mx = p[0];
#pragma unroll
  for (int m = 1; m < 24; m++) mx = fmaxf(mx, p[m]);
  float s = 0.f;
#pragma unroll
  for (int m = 0; m < 24; m++){ p[m] = expf(p[m] - mx); s += p[m]; }
  float inv = 1.f / s;
  float s0 = 0.f, s1 = 0.f, s2 = 0.f;
#pragma unroll
  for (int m = 0; m < 24; m++){
    float a = p[m] * inv;
    p[m] = a;
    if (t > 0) s0 = fmaf(a, W0[row * 24 + m], s0);
    if (t > 1) s1 = fmaf(a, W1[row * 24 + m], s1);
    if (t > 2) s2 = fmaf(a, W2[row * 24 + m], s2);
  }
  if (lane == 0){
#pragma unroll
    for (int m = 0; m < 24; m++) ubuf[row * 24 + m] = p[m] * Ac[row * 24 + m];
    sval[row * 4 + 0] = s0; sval[row * 4 + 1] = s1; sval[row * 4 + 2] = s2;
  }
}

// ---------------- mem_ctx = u @ init + sum_tau s_tau * wv_tau ------------------
__global__ __launch_bounds__(256)
void mem_ctx_kernel(const float* __restrict__ ubuf, const float* __restrict__ mvi,
                    const float* __restrict__ sval, const float* __restrict__ wv0,
                    const float* __restrict__ wv1, const float* __restrict__ wv2,
                    float* __restrict__ mctx, int t)
{
  int row = blockIdx.x;
  int tid = threadIdx.x;
  __shared__ float su[24];
  __shared__ float ss[3];
  if (tid < 24) su[tid] = ubuf[row * 24 + tid];
  if (tid >= 32 && tid < 35) ss[tid - 32] = sval[row * 4 + (tid - 32)];
  __syncthreads();
  for (int d = tid; d < IN_D; d += 256){
    float v = 0.f;
#pragma unroll
    for (int m = 0; m < 24; m++) v = fmaf(su[m], mvi[m * IN_D + d], v);
    size_t idx = (size_t)row * IN_D + d;
    if (t > 0) v = fmaf(ss[0], wv0[idx], v);
    if (t > 1) v = fmaf(ss[1], wv1[idx], v);
    if (t > 2) v = fmaf(ss[2], wv2[idx], v);
    mctx[idx] = v;
  }
}

// ---------------- depth attention over <=3 cached bank items -------------------
__global__ __launch_bounds__(256)
void depth_kernel(const float* __restrict__ q, const float* __restrict__ k0p,
                  const float* __restrict__ k1p, const float* __restrict__ k2p,
                  const float* __restrict__ v0p, const float* __restrict__ v1p,
                  const float* __restrict__ v2p, float* __restrict__ dctx, int t)
{
  int lane = threadIdx.x & 63;
  int row = blockIdx.x * 4 + (threadIdx.x >> 6);
  size_t rb = (size_t)row * IN_D;
  float a0 = 0.f, a1 = 0.f, a2 = 0.f;
  for (int k = lane; k < IN_D; k += 64){
    float qv = q[rb + k];
    a0 = fmaf(qv, k0p[rb + k], a0);
    if (t > 1) a1 = fmaf(qv, k1p[rb + k], a1);
    if (t > 2) a2 = fmaf(qv, k2p[rb + k], a2);
  }
  a0 = wred(a0) * 0.03125f; a1 = wred(a1) * 0.03125f; a2 = wred(a2) * 0.03125f;
  float mx = a0;
  if (t > 1) mx = fmaxf(mx, a1);
  if (t > 2) mx = fmaxf(mx, a2);
  float e0 = expf(a0 - mx);
  float e1 = (t > 1) ? expf(a1 - mx) : 0.f;
  float e2 = (t > 2) ? expf(a2 - mx) : 0.f;
  float inv = 1.f / (e0 + e1 + e2);
  e0 *= inv; e1 *= inv; e2 *= inv;
  for (int k = lane; k < IN_D; k += 64){
    float v = e0 * v0p[rb + k];
    if (t > 1) v = fmaf(e1, v1p[rb + k], v);
    if (t > 2) v = fmaf(e2, v2p[rb + k], v);
    dctx[rb + k] = v;
  }
}

// ---------------- ssm first stage: tanh(cur @ ssm_a_w^T + b) -------------------
__global__ __launch_bounds__(256)
void ssm_a_kernel(const float* __restrict__ cur, const float* __restrict__ saw,
                  const float* __restrict__ sab, float* __restrict__ t40)
{
  int lane = threadIdx.x & 63;
  int row = blockIdx.x * 4 + (threadIdx.x >> 6);
  size_t rb = (size_t)row * IN_D;
  float p[40];
#pragma unroll
  for (int o = 0; o < 40; o++) p[o] = 0.f;
  for (int k = lane; k < IN_D; k += 64){
    float cv = cur[rb + k];
#pragma unroll
    for (int o = 0; o < 40; o++) p[o] = fmaf(cv, saw[o * IN_D + k], p[o]);
  }
#pragma unroll
  for (int o = 0; o < 40; o++) p[o] = wred(p[o]);
  if (lane == 0){
#pragma unroll
    for (int o = 0; o < 40; o++) t40[row * 40 + o] = tanhf(p[o] + sab[o]);
  }
}

// ---------------- enriched + LN (fuses ssm second stage) -----------------------
__global__ __launch_bounds__(256)
void enriched_kernel(const float* __restrict__ cur, const float* __restrict__ mctx,
                     const float* __restrict__ dctx, const float* __restrict__ t40,
                     const float* __restrict__ sbw, const float* __restrict__ sbb,
                     const float* __restrict__ lng, const float* __restrict__ lnbv,
                     float* __restrict__ enr, float* __restrict__ lnout, int t)
{
  int row = blockIdx.x;
  int tid = threadIdx.x;
  __shared__ float s40[40];
  __shared__ float red[8];
  if (tid < 40) s40[tid] = t40[row * 40 + tid];
  __syncthreads();
  float ev[4];
  float part = 0.f;
#pragma unroll
  for (int j = 0; j < 4; j++){
    int d = tid + j * 256;
    float sv = sbb[d];
#pragma unroll
    for (int o = 0; o < 40; o++) sv = fmaf(s40[o], sbw[d * 40 + o], sv);
    size_t idx = (size_t)row * IN_D + d;
    float v = cur[idx] + 0.34f * mctx[idx] + 0.22f * dctx[idx] + 0.18f * sv;
    ev[j] = v; part += v;
  }
  part = wred(part);
  if ((tid & 63) == 0) red[tid >> 6] = part;
  __syncthreads();
  float mean = (red[0] + red[1] + red[2] + red[3]) * (1.f / 1024.f);
  float vp = 0.f;
#pragma unroll
  for (int j = 0; j < 4; j++){ float dd = ev[j] - mean; vp += dd * dd; }
  vp = wred(vp);
  if ((tid & 63) == 0) red[4 + (tid >> 6)] = vp;
  __syncthreads();
  float var = (red[4] + red[5] + red[6] + red[7]) * (1.f / 1024.f);
  float rs = 1.f / sqrtf(var + 1e-5f);
#pragma unroll
  for (int j = 0; j < 4; j++){
    int d = tid + j * 256;
    size_t idx = (size_t)row * IN_D + d;
    enr[idx] = ev[j];
    lnout[idx] = (ev[j] - mean) * rs * lng[t * IN_D + d] + lnbv[t * IN_D + d];
  }
}

// ---------------- routing: gates, budget, top-k, wg, halt, coeff update --------
__global__ __launch_bounds__(256)
void routing_kernel(const float* __restrict__ cur, const float* __restrict__ mctx,
                    const float* __restrict__ dctx,
                    const float* __restrict__ msw, const float* __restrict__ msb,
                    const float* __restrict__ mmw, const float* __restrict__ mmb,
                    const float* __restrict__ ebias,
                    const float* __restrict__ bw, const float* __restrict__ bb,
                    const float* __restrict__ wgw, const float* __restrict__ wgb,
                    const float* __restrict__ hw, const float* __restrict__ hb,
                    float* __restrict__ sg, float* __restrict__ haltb,
                    float* __restrict__ Ac, float* __restrict__ W0,
                    float* __restrict__ W1, float* __restrict__ W2, int t)
{
  int lane = threadIdx.x & 63;
  int row = blockIdx.x * 4 + (threadIdx.x >> 6);
  size_t rb = (size_t)row * IN_D;
  float ps[40], pw[24], pm[4], pb[4], ph = 0.f;
#pragma unroll
  for (int o = 0; o < 40; o++) ps[o] = 0.f;
#pragma unroll
  for (int m = 0; m < 24; m++) pw[m] = 0.f;
#pragma unroll
  for (int o = 0; o < 4; o++){ pm[o] = 0.f; pb[o] = 0.f; }
  const float* hwt = hw + t * IN_D;
  for (int k = lane; k < IN_D; k += 64){
    float cv = cur[rb + k], mv = mctx[rb + k], dv = dctx[rb + k];
#pragma unroll
    for (int o = 0; o < 40; o++) ps[o] = fmaf(cv, msw[o * IN_D + k], ps[o]);
#pragma unroll
    for (int o = 0; o < 4; o++) pm[o] = fmaf(cv, mmw[o * IN_D + k], pm[o]);
#pragma unroll
    for (int o = 0; o < 4; o++) pb[o] = fmaf(cv, bw[o * IN_D + k], pb[o]);
#pragma unroll
    for (int m = 0; m < 24; m++){
      float t1 = fmaf(cv, wgw[m * 2048 + k], pw[m]);
      pw[m] = fmaf(mv, wgw[m * 2048 + 1024 + k], t1);
    }
    ph = fmaf(cv + 0.2f * mv + 0.1f * dv, hwt[k], ph);
  }
#pragma unroll
  for (int o = 0; o < 40; o++) ps[o] = wred(ps[o]);
#pragma unroll
  for (int m = 0; m < 24; m++) pw[m] = wred(pw[m]);
#pragma unroll
  for (int o = 0; o < 4; o++){ pm[o] = wred(pm[o]); pb[o] = wred(pb[o]); }
  ph = wred(ph);

  // mix softmax
#pragma unroll
  for (int o = 0; o < 4; o++) pm[o] += mmb[o];
  float mmx = fmaxf(fmaxf(pm[0], pm[1]), fmaxf(pm[2], pm[3]));
  float msum = 0.f;
#pragma unroll
  for (int o = 0; o < 4; o++){ pm[o] = expf(pm[o] - mmx); msum += pm[o]; }
  float minv = 1.f / msum;
  // gate logits -> softmax probs
  float gl[10];
#pragma unroll
  for (int e = 0; e < 10; e++){
    float g = ebias[e];
#pragma unroll
    for (int s2 = 0; s2 < 4; s2++) g = fmaf(pm[s2] * minv, ps[s2 * 10 + e] + msb[s2 * 10 + e], g);
    gl[e] = g;
  }
  float gmx = gl[0];
#pragma unroll
  for (int e = 1; e < 10; e++) gmx = fmaxf(gmx, gl[e]);
  float gs = 0.f;
#pragma unroll
  for (int e = 0; e < 10; e++){ gl[e] = expf(gl[e] - gmx); gs += gl[e]; }
  float ginv = 1.f / gs;
#pragma unroll
  for (int e = 0; e < 10; e++) gl[e] *= ginv;
  // budget = 1 + argmax (first max wins, matches jnp.argmax)
#pragma unroll
  for (int o = 0; o < 4; o++) pb[o] += bb[o];
  int bud = 1; float bbest = pb[0];
  if (pb[1] > bbest){ bbest = pb[1]; bud = 2; }
  if (pb[2] > bbest){ bbest = pb[2]; bud = 3; }
  if (pb[3] > bbest){ bbest = pb[3]; bud = 4; }
  // top-4 (strict > keeps lowest index on ties, matches lax.top_k)
  float tv[4]; int ti[4]; unsigned used = 0;
#pragma unroll
  for (int j = 0; j < 4; j++){
    float best = -1e30f; int bi = 0;
#pragma unroll
    for (int e = 0; e < 10; e++){
      bool ok = (!((used >> e) & 1u)) && (gl[e] > best);
      if (ok){ best = gl[e]; bi = e; }
    }
    tv[j] = best; ti[j] = bi; used |= (1u << bi);
  }
  float ssum = tv[0];
  if (bud > 1) ssum += tv[1];
  if (bud > 2) ssum += tv[2];
  if (bud > 3) ssum += tv[3];
  float den = fmaxf(ssum, 1e-6f);
  float sup = 1.f - tv[0] / den;
  // wg softmax
#pragma unroll
  for (int m = 0; m < 24; m++) pw[m] += wgb[m];
  float wmx = pw[0];
#pragma unroll
  for (int m = 1; m < 24; m++) wmx = fmaxf(wmx, pw[m]);
  float wsum = 0.f;
#pragma unroll
  for (int m = 0; m < 24; m++){ pw[m] = expf(pw[m] - wmx); wsum += pw[m]; }
  float winv = 1.f / wsum;
  float hv = 1.f / (1.f + expf(-(ph + hb[t])));

  if (lane == 0){
#pragma unroll
    for (int e = 0; e < 10; e++){
      float sv = 0.f;
#pragma unroll
      for (int j = 0; j < 4; j++) if (j < bud && ti[j] == e) sv = tv[j] / den;
      sg[row * 10 + e] = sv;
    }
    haltb[row] = hv;
#pragma unroll
    for (int m = 0; m < 24; m++){
      float c = sup * pw[m] * winv;
      float om = 1.f - c;
      Ac[row * 24 + m] *= om;
      if (t > 0) W0[row * 24 + m] *= om;
      if (t > 1) W1[row * 24 + m] *= om;
      if (t > 2) W2[row * 24 + m] *= om;
      if (t == 0)      W0[row * 24 + m] = c;
      else if (t == 1) W1[row * 24 + m] = c;
      else if (t == 2) W2[row * 24 + m] = c;
    }
  }
}

// ---------------- finalize step: total += remaining*step_logits ----------------
__global__ __launch_bounds__(256)
void finalize_kernel(const float* __restrict__ mctx, const float* __restrict__ dctx,
                     const float* __restrict__ mow, const float* __restrict__ dow,
                     const float* __restrict__ EL, const float* __restrict__ haltb,
                     float* __restrict__ total, float* __restrict__ cumh)
{
  int lane = threadIdx.x & 63;
  int row = blockIdx.x * 4 + (threadIdx.x >> 6);
  size_t rb = (size_t)row * IN_D;
  float p1[10], p2[10];
#pragma unroll
  for (int o = 0; o < 10; o++){ p1[o] = 0.f; p2[o] = 0.f; }
  for (int k = lane; k < IN_D; k += 64){
    float mv = mctx[rb + k], dv = dctx[rb + k];
#pragma unroll
    for (int o = 0; o < 10; o++){
      p1[o] = fmaf(mv, mow[o * IN_D + k], p1[o]);
      p2[o] = fmaf(dv, dow[o * IN_D + k], p2[o]);
    }
  }
#pragma unroll
  for (int o = 0; o < 10; o++){ p1[o] = wred(p1[o]); p2[o] = wred(p2[o]); }
  if (lane == 0){
    float rem = 1.f - cumh[row];
#pragma unroll
    for (int o = 0; o < 10; o++)
      total[row * 10 + o] += rem * (EL[row * 10 + o] + 0.22f * p1[o] + 0.14f * p2[o]);
    cumh[row] += rem * haltb[row];
  }
}

// ---------------- base = x@weight^T + bias -------------------------------------
__global__ __launch_bounds__(256)
void base_kernel(const float* __restrict__ x, const float* __restrict__ w,
                 const float* __restrict__ b, float* __restrict__ outp)
{
  int lane = threadIdx.x & 63;
  int row = blockIdx.x * 4 + (threadIdx.x >> 6);
  size_t rb = (size_t)row * IN_D;
  float p[10];
#pragma unroll
  for (int o = 0; o < 10; o++) p[o] = 0.f;
  for (int k = lane; k < IN_D; k += 64){
    float xv = x[rb + k];
#pragma unroll
    for (int o = 0; o < 10; o++) p[o] = fmaf(xv, w[o * IN_D + k], p[o]);
  }
#pragma unroll
  for (int o = 0; o < 10; o++) p[o] = wred(p[o]);
  if (lane == 0){
#pragma unroll
    for (int o = 0; o < 10; o++) outp[row * 10 + o] = p[o] + b[o];
  }
}

// ---------------- shared branch: LN(shared_pre @ sdw^T) ------------------------
__global__ __launch_bounds__(256)
void shared_kernel(const float* __restrict__ shpre, const float* __restrict__ sdw,
                   const float* __restrict__ g, const float* __restrict__ b,
                   float* __restrict__ outp)
{
  int lane = threadIdx.x & 63;
  int row = blockIdx.x * 4 + (threadIdx.x >> 6);
  const float* xr = shpre + (size_t)row * SHD;
  float p[10];
#pragma unroll
  for (int o = 0; o < 10; o++) p[o] = 0.f;
  for (int k = lane; k < SHD; k += 64){
    float xv = xr[k];
#pragma unroll
    for (int o = 0; o < 10; o++) p[o] = fmaf(xv, sdw[o * SHD + k], p[o]);
  }
#pragma unroll
  for (int o = 0; o < 10; o++) p[o] = wred(p[o]);
  float mean = 0.f;
#pragma unroll
  for (int o = 0; o < 10; o++) mean += p[o];
  mean *= 0.1f;
  float var = 0.f;
#pragma unroll
  for (int o = 0; o < 10; o++){ float dd = p[o] - mean; var += dd * dd; }
  var *= 0.1f;
  float rs = 1.f / sqrtf(var + 1e-5f);
  if (lane == 0){
#pragma unroll
    for (int o = 0; o < 10; o++) outp[row * 10 + o] = (p[o] - mean) * rs * g[o] + b[o];
  }
}

// ---------------- final output --------------------------------------------------
__global__ __launch_bounds__(256)
void final_out_kernel(const float* __restrict__ cur, const float* __restrict__ mow,
                      const float* __restrict__ basep, const float* __restrict__ sharedp,
                      const float* __restrict__ total, const float* __restrict__ sscale,
                      const float* __restrict__ alphap, const float* __restrict__ betap,
                      float* __restrict__ outp)
{
  int lane = threadIdx.x & 63;
  int row = blockIdx.x * 4 + (threadIdx.x >> 6);
  size_t rb = (size_t)row * IN_D;
  float p[10];
#pragma unroll
  for (int o = 0; o < 10; o++) p[o] = 0.f;
  for (int k = lane; k < IN_D; k += 64){
    float cv = cur[rb + k];
#pragma unroll
    for (int o = 0; o < 10; o++) p[o] = fmaf(cv, mow[o * IN_D + k], p[o]);
  }
#pragma unroll
  for (int o = 0; o < 10; o++) p[o] = wred(p[o]);
  if (lane == 0){
    float ss = sscale[0], av = alphap[0] + 1e-4f, bv = betap[0];
#pragma unroll
    for (int o = 0; o < 10; o++)
      outp[row * 10 + o] = basep[row * 10 + o] + ss * sharedp[row * 10 + o]
                         + av * (total[row * 10 + o] * 0.25f) + bv * p[o];
  }
}

// ---------------- utility kernels ----------------------------------------------
__global__ void cvt_bf16_kernel(const float* __restrict__ src, uint16_t* __restrict__ dst, size_t n){
  size_t i = (size_t)blockIdx.x * blockDim.x + threadIdx.x;
  size_t stride = (size_t)gridDim.x * blockDim.x;
  for (; i < n; i += stride) dst[i] = f2bf(src[i]);
}
__global__ void fill1_kernel(float* __restrict__ p, int n){
  int i = blockIdx.x * blockDim.x + threadIdx.x;
  if (i < n) p[i] = 1.f;
}

// ================================================================================
extern "C" void kernel_launch(void* const* d_in, const int* in_sizes, int n_in,
                              void* d_out, int out_size, void* d_ws, size_t ws_size,
                              hipStream_t stream)
{
  const float* x     = (const float*)d_in[0];
  const float* wgt   = (const float*)d_in[1];
  const float* bias  = (const float*)d_in[2];
  const float* suw   = (const float*)d_in[3];
  const float* sdw   = (const float*)d_in[4];
  const float* sng   = (const float*)d_in[5];
  const float* snb   = (const float*)d_in[6];
  const float* sscale= (const float*)d_in[7];
  const float* keys  = (const float*)d_in[8];
  const float* mvi   = (const float*)d_in[9];
  const float* mqw   = (const float*)d_in[10];
  const float* mow   = (const float*)d_in[11];
  const float* wgw   = (const float*)d_in[12];
  const float* wgb   = (const float*)d_in[13];
  const float* wvw   = (const float*)d_in[14];
  const float* wvb   = (const float*)d_in[15];
  const float* dqw   = (const float*)d_in[16];
  const float* dkw   = (const float*)d_in[17];
  const float* dvw   = (const float*)d_in[18];
  const float* dow   = (const float*)d_in[19];
  const float* clng  = (const float*)d_in[20];
  const float* clnb  = (const float*)d_in[21];
  const float* fc1w  = (const float*)d_in[22];
  const float* fc1b  = (const float*)d_in[23];
  const float* fc2w  = (const float*)d_in[24];
  const float* fc2b  = (const float*)d_in[25];
  const float* saw   = (const float*)d_in[26];
  const float* sab   = (const float*)d_in[27];
  const float* sbw   = (const float*)d_in[28];
  const float* sbb   = (const float*)d_in[29];
  const float* msw   = (const float*)d_in[30];
  const float* msb   = (const float*)d_in[31];
  const float* mmw   = (const float*)d_in[32];
  const float* mmb   = (const float*)d_in[33];
  const float* ebias = (const float*)d_in[34];
  const float* bw    = (const float*)d_in[35];
  const float* bb    = (const float*)d_in[36];
  const float* eup   = (const float*)d_in[37];
  const float* edn   = (const float*)d_in[38];
  const float* eng   = (const float*)d_in[39];
  const float* enb   = (const float*)d_in[40];
  const float* hw    = (const float*)d_in[41];
  const float* hb    = (const float*)d_in[42];
  const float* alphap= (const float*)d_in[43];
  const float* betap = (const float*)d_in[44];
  float* outp = (float*)d_out;

  char* wsb = (char*)d_ws;
  size_t off = 0;
  auto AL = [&](size_t bytes) -> void* {
    void* p = wsb + off;
    off = (off + bytes + 255) & ~(size_t)255;
    return p;
  };
  const size_t NI = (size_t)N_TOK * IN_D;
  float* cur    = (float*)AL(NI * 4);
  float* enr    = (float*)AL(NI * 4);
  float* lnbuf  = (float*)AL(NI * 4);
  float* h768   = (float*)AL((size_t)N_TOK * INNER * 4);
  float* mq     = (float*)AL(NI * 4);              // reused as q
  float* mctx   = (float*)AL(NI * 4);
  float* dctx   = (float*)AL(NI * 4);
  float* t40    = (float*)AL((size_t)N_TOK * 40 * 4);
  float* wv0    = (float*)AL(NI * 4);
  float* wv1    = (float*)AL(NI * 4);
  float* wv2    = (float*)AL(NI * 4);
  float* kc0    = (float*)AL(NI * 4);
  float* kc1    = (float*)AL(NI * 4);
  float* kc2    = (float*)AL(NI * 4);
  float* vc0    = (float*)AL(NI * 4);
  float* vc1    = (float*)AL(NI * 4);
  float* vc2    = (float*)AL(NI * 4);
  float* ubuf   = (float*)AL((size_t)N_TOK * 24 * 4);
  float* sval   = (float*)AL((size_t)N_TOK * 4 * 4);
  float* Ac     = (float*)AL((size_t)N_TOK * 24 * 4);
  float* W0     = (float*)AL((size_t)N_TOK * 24 * 4);
  float* W1     = (float*)AL((size_t)N_TOK * 24 * 4);
  float* W2     = (float*)AL((size_t)N_TOK * 24 * 4);
  float* sg     = (float*)AL((size_t)N_TOK * 10 * 4);
  float* haltb  = (float*)AL((size_t)N_TOK * 4);
  float* EL     = (float*)AL((size_t)N_TOK * 10 * 4);
  float* total  = (float*)AL((size_t)N_TOK * 10 * 4);
  float* cumh   = (float*)AL((size_t)N_TOK * 4);
  float* basep  = (float*)AL((size_t)N_TOK * 10 * 4);
  float* sharedp= (float*)AL((size_t)N_TOK * 10 * 4);
  uint16_t* curbf = (uint16_t*)AL(NI * 2);
  uint16_t* upbf  = (uint16_t*)AL((size_t)NEXP * DMAX * IN_D * 2);
  uint16_t* hh    = (uint16_t*)AL((size_t)N_TOK * DSUM * 2);
  float* shpre  = (float*)hh;   // alias: shpre consumed before hh is written

  // ---- init (re-done every launch: deterministic) ----
  hipMemsetAsync(dctx, 0, NI * 4, stream);
  hipMemsetAsync(total, 0, (size_t)N_TOK * 10 * 4, stream);
  hipMemsetAsync(cumh, 0, (size_t)N_TOK * 4, stream);
  hipMemcpyAsync(cur, x, NI * 4, hipMemcpyDeviceToDevice, stream);
  fill1_kernel<<<(N_TOK * 24 + 255) / 256, 256, 0, stream>>>(Ac, N_TOK * 24);
  cvt_bf16_kernel<<<4096, 256, 0, stream>>>(eup, upbf, (size_t)NEXP * DMAX * IN_D);

  base_kernel<<<512, 256, 0, stream>>>(x, wgt, bias, basep);
  gemm_f32<EPI_SILU><<<dim3(SHD / 64, N_TOK / 64), 256, 0, stream>>>(
      x, suw, nullptr, nullptr, shpre, IN_D, SHD);
  shared_kernel<<<512, 256, 0, stream>>>(shpre, sdw, sng, snb, sharedp);

  float* wvB[3] = {wv0, wv1, wv2};
  float* kcB[3] = {kc0, kc1, kc2};
  float* vcB[3] = {vc0, vc1, vc2};

  for (int t = 0; t < NSTEP; t++){
    // memory attention path
    gemm_f32<EPI_NONE><<<dim3(16, 32), 256, 0, stream>>>(cur, mqw, nullptr, nullptr, mq, IN_D, IN_D);
    mem_attn_kernel<<<512, 256, 0, stream>>>(mq, keys, Ac, W0, W1, W2, ubuf, sval, t);
    mem_ctx_kernel<<<2048, 256, 0, stream>>>(ubuf, mvi, sval, wv0, wv1, wv2, mctx, t);
    // depth attention path
    if (t > 0){
      gemm_f32<EPI_NONE><<<dim3(16, 32), 256, 0, stream>>>(cur, dqw, nullptr, nullptr, mq, IN_D, IN_D);
      depth_kernel<<<512, 256, 0, stream>>>(mq, kc0, kc1, kc2, vc0, vc1, vc2, dctx, t);
    }
    // ssm + enriched + LN
    ssm_a_kernel<<<512, 256, 0, stream>>>(cur, saw, sab, t40);
    enriched_kernel<<<2048, 256, 0, stream>>>(cur, mctx, dctx, t40, sbw, sbb, clng, clnb, enr, lnbuf, t);
    // cell MLP
    gemm_f32<EPI_GELU_BIAS><<<dim3(INNER / 64, 32), 256, 0, stream>>>(
        lnbuf, fc1w + (size_t)t * INNER * IN_D, fc1b + t * INNER, nullptr, h768, IN_D, INNER);
    gemm_f32<EPI_ADD_BIAS><<<dim3(16, 32), 256, 0, stream>>>(
        h768, fc2w + (size_t)t * IN_D * INNER, fc2b + t * IN_D, enr, cur, INNER, IN_D);
    // bank projections + wv for future steps
    if (t < 3){
      gemm_f32<EPI_NONE><<<dim3(16, 32), 256, 0, stream>>>(cur, dkw, nullptr, nullptr, kcB[t], IN_D, IN_D);
      gemm_f32<EPI_NONE><<<dim3(16, 32), 256, 0, stream>>>(cur, dvw, nullptr, nullptr, vcB[t], IN_D, IN_D);
      gemm_f32<EPI_BIAS><<<dim3(16, 32), 256, 0, stream>>>(cur, wvw, wvb, nullptr, wvB[t], IN_D, IN_D);
    }
    cvt_bf16_kernel<<<2048, 256, 0, stream>>>(cur, curbf, NI);
    // routing / gates / coeff update
    routing_kernel<<<512, 256, 0, stream>>>(cur, mctx, dctx, msw, msb, mmw, mmb, ebias,
                                            bw, bb, wgw, wgb, hw, hb,
                                            sg, haltb, Ac, W0, W1, W2, t);
    // experts
    expert_up_mfma<<<dim3(16, 26, 10), 256, 0, stream>>>(curbf, upbf, hh);
    expert_down<<<512, 256, 0, stream>>>(hh, edn, sg, eng, enb, EL);
    // accumulate step logits
    finalize_kernel<<<512, 256, 0, stream>>>(mctx, dctx, mow, dow, EL, haltb, total, cumh);
  }
  final_out_kernel<<<512, 256, 0, stream>>>(cur, mow, basep, sharedp, total, sscale,
                                            alphap, betap, outp);
}

// Round 2
// 4854.907 us; speedup vs baseline: 1.7783x; 1.7783x over previous
//
#include <hip/hip_runtime.h>
#include <stdint.h>

#define N_TOK 2048
#define IN_D  1024
#define OUT_D 10
#define NEXP  10
#define MMEM  24
#define NSTEP 4
#define NDST  40
#define INNER 768
#define SHD   2048
#define DMAX  3328
#define DSUM  24064

typedef __attribute__((ext_vector_type(4))) float f32x4;
typedef __attribute__((ext_vector_type(8))) short bf16x8;

__device__ const int c_dims[10] = {1536,2048,2560,3072,1792,2304,2816,2048,2560,3328};
__device__ const int c_offs[10] = {0,1536,3584,6144,9216,11008,13312,16128,18176,20736};
__device__ const int c_acts[10] = {0,1,2,3,4,5,6,7,0,1};

__device__ __forceinline__ float wred(float v){
#pragma unroll
  for (int s = 32; s > 0; s >>= 1) v += __shfl_xor(v, s, 64);
  return v;
}

__device__ __forceinline__ float bf2f(uint16_t u){
  return __uint_as_float(((uint32_t)u) << 16);
}
__device__ __forceinline__ uint16_t f2bf(float f){
  uint32_t u = __float_as_uint(f);
  return (uint16_t)((u + 0x7FFFu + ((u >> 16) & 1u)) >> 16);
}

// async global->LDS, 16B per lane (wave-uniform LDS base + lane*16)
__device__ __forceinline__ void gload16(const uint16_t* g, uint16_t* l){
  __builtin_amdgcn_global_load_lds(
      (const __attribute__((address_space(1))) uint32_t*)(const void*)g,
      (__attribute__((address_space(3))) uint32_t*)(void*)l, 16, 0, 0);
}

__device__ __forceinline__ float actf(int a, float x){
  switch(a){
    case 0: return x / (1.f + expf(-x));                               // silu
    case 1: return 0.5f * x * (1.f + erff(x * 0.7071067811865475f));   // gelu exact
    case 2: { float sp = fmaxf(x,0.f) + log1pf(expf(-fabsf(x)));       // mish
              return x * tanhf(sp); }
    case 3: return fmaxf(x, 0.f);                                      // relu
    case 4: return x > 0.f ? 1.0507009873554805f * x                   // selu
                           : 1.7580993408473768f * expm1f(x);
    case 5: return tanhf(x);                                           // tanh
    case 6: return fmaxf(x,0.f) + log1pf(expf(-fabsf(x)));             // softplus
    default: return x > 0.f ? x : expm1f(x);                           // elu
  }
}

// ---------------- f32 -> (hi, lo) bf16 split -----------------------------------
__global__ void split_kernel(const float* __restrict__ src, uint16_t* __restrict__ hi,
                             uint16_t* __restrict__ lo, size_t n){
  size_t i = ((size_t)blockIdx.x * blockDim.x + threadIdx.x) << 2;
  size_t stride = ((size_t)gridDim.x * blockDim.x) << 2;
  for (; i < n; i += stride){
    float4 v = *(const float4*)(src + i);
    ushort4 h, l;
    h.x = f2bf(v.x); l.x = f2bf(v.x - bf2f(h.x));
    h.y = f2bf(v.y); l.y = f2bf(v.y - bf2f(h.y));
    h.z = f2bf(v.z); l.z = f2bf(v.z - bf2f(h.z));
    h.w = f2bf(v.w); l.w = f2bf(v.w - bf2f(h.w));
    *(ushort4*)(hi + i) = h;
    *(ushort4*)(lo + i) = l;
  }
}

// ---------------- split-bf16 MFMA GEMM: C = epi(A @ W^T), ~f32 precision -------
// A = Ah+Al [N,K] bf16 pairs, W = Wh+Wl [D,K]. 128x128 tile, K-step 32.
enum { EPI_NONE=0, EPI_BIAS=1, EPI_GELU_BIAS=2, EPI_ADD_BIAS=3, EPI_SILU=4 };

template<int EPI>
__global__ __launch_bounds__(256)
void gemm_sp(const uint16_t* __restrict__ Ah, const uint16_t* __restrict__ Al,
             const uint16_t* __restrict__ Wh, const uint16_t* __restrict__ Wl,
             const float* __restrict__ bias, const float* __restrict__ addend,
             float* __restrict__ C, int K, int D)
{
  __shared__ __align__(16) uint16_t sAh[128*32];
  __shared__ __align__(16) uint16_t sAl[128*32];
  __shared__ __align__(16) uint16_t sWh[128*32];
  __shared__ __align__(16) uint16_t sWl[128*32];
  int tid = threadIdx.x, lane = tid & 63, wave = tid >> 6;
  int wr = wave >> 1, wc = wave & 1;
  int arow = lane & 15, agrp = lane >> 4;
  int rowBase = blockIdx.y * 128, colBase = blockIdx.x * 128;
  f32x4 acc[4][4];
#pragma unroll
  for (int m = 0; m < 4; m++)
#pragma unroll
    for (int n = 0; n < 4; n++){ f32x4 z = {0.f,0.f,0.f,0.f}; acc[m][n] = z; }

  for (int k0 = 0; k0 < K; k0 += 32){
#pragma unroll
    for (int s = 0; s < 2; s++){
      int c = tid + s * 256;
      int rr = c >> 2, cc = (c & 3) << 3;
      size_t ga = (size_t)(rowBase + rr) * K + k0 + cc;
      size_t gw = (size_t)(colBase + rr) * K + k0 + cc;
      gload16(&Ah[ga], &sAh[c << 3]);
      gload16(&Al[ga], &sAl[c << 3]);
      gload16(&Wh[gw], &sWh[c << 3]);
      gload16(&Wl[gw], &sWl[c << 3]);
    }
    __syncthreads();
    bf16x8 ah[4], al[4], bh[4], bl[4];
#pragma unroll
    for (int m = 0; m < 4; m++){
      int ro = (wr*64 + m*16 + arow) * 32 + agrp * 8;
      ah[m] = *(const bf16x8*)&sAh[ro];
      al[m] = *(const bf16x8*)&sAl[ro];
    }
#pragma unroll
    for (int n = 0; n < 4; n++){
      int ro = (wc*64 + n*16 + arow) * 32 + agrp * 8;
      bh[n] = *(const bf16x8*)&sWh[ro];
      bl[n] = *(const bf16x8*)&sWl[ro];
    }
#pragma unroll
    for (int m = 0; m < 4; m++)
#pragma unroll
      for (int n = 0; n < 4; n++){
        acc[m][n] = __builtin_amdgcn_mfma_f32_16x16x32_bf16(ah[m], bh[n], acc[m][n], 0, 0, 0);
        acc[m][n] = __builtin_amdgcn_mfma_f32_16x16x32_bf16(ah[m], bl[n], acc[m][n], 0, 0, 0);
        acc[m][n] = __builtin_amdgcn_mfma_f32_16x16x32_bf16(al[m], bh[n], acc[m][n], 0, 0, 0);
      }
    __syncthreads();
  }
#pragma unroll
  for (int m = 0; m < 4; m++){
#pragma unroll
    for (int n = 0; n < 4; n++){
      int col = colBase + wc*64 + n*16 + arow;
#pragma unroll
      for (int r2 = 0; r2 < 4; r2++){
        int row = rowBase + wr*64 + m*16 + agrp*4 + r2;
        float v = acc[m][n][r2];
        if (EPI == EPI_BIAS || EPI == EPI_GELU_BIAS || EPI == EPI_ADD_BIAS) v += bias[col];
        if (EPI == EPI_GELU_BIAS) v = 0.5f * v * (1.f + erff(v * 0.7071067811865475f));
        if (EPI == EPI_SILU)      v = v / (1.f + expf(-v));
        if (EPI == EPI_ADD_BIAS)  v += addend[(size_t)row * D + col];
        C[(size_t)row * D + col] = v;
      }
    }
  }
}

// ---------------- expert up-projection, bf16 MFMA, coalesced epilogue ----------
__global__ __launch_bounds__(256)
void expert_up_mfma(const uint16_t* __restrict__ Abf, const uint16_t* __restrict__ Ubf,
                    uint16_t* __restrict__ HH)
{
  int e = blockIdx.z;
  int dcols = c_dims[e];
  int ct = blockIdx.y;
  if (ct * 128 >= dcols) return;
  const uint16_t* W = Ubf + (size_t)e * DMAX * IN_D + (size_t)ct * 128 * IN_D;
  int rowBase = blockIdx.x * 128;
  __shared__ __align__(16) uint16_t smem[16384];   // As|Bs (16KB) then Ht (32KB)
  uint16_t* As = smem;
  uint16_t* Bs = smem + 4096;
  int tid = threadIdx.x, lane = tid & 63, wave = tid >> 6;
  int wr = wave >> 1, wc = wave & 1;
  int arow = lane & 15, agrp = lane >> 4;
  f32x4 acc[4][4];
#pragma unroll
  for (int m = 0; m < 4; m++)
#pragma unroll
    for (int n = 0; n < 4; n++){ f32x4 z = {0.f,0.f,0.f,0.f}; acc[m][n] = z; }

  for (int k0 = 0; k0 < IN_D; k0 += 32){
#pragma unroll
    for (int s = 0; s < 2; s++){
      int c = tid + s * 256;
      int rr = c >> 2, cc = (c & 3) << 3;
      gload16(&Abf[(size_t)(rowBase + rr) * IN_D + k0 + cc], &As[c << 3]);
      gload16(&W[(size_t)rr * IN_D + k0 + cc], &Bs[c << 3]);
    }
    __syncthreads();
    bf16x8 a[4], b[4];
#pragma unroll
    for (int m = 0; m < 4; m++) a[m] = *(const bf16x8*)&As[(wr*64 + m*16 + arow) * 32 + agrp * 8];
#pragma unroll
    for (int n = 0; n < 4; n++) b[n] = *(const bf16x8*)&Bs[(wc*64 + n*16 + arow) * 32 + agrp * 8];
#pragma unroll
    for (int m = 0; m < 4; m++)
#pragma unroll
      for (int n = 0; n < 4; n++)
        acc[m][n] = __builtin_amdgcn_mfma_f32_16x16x32_bf16(a[m], b[n], acc[m][n], 0, 0, 0);
    __syncthreads();
  }
  // epilogue: activation -> swizzled LDS tile -> coalesced 16B global stores
  int actid = c_acts[e];
  uint16_t* Ht = smem;   // full 32KB, safe after trailing barrier above
#pragma unroll
  for (int m = 0; m < 4; m++){
    int rb0 = wr*64 + m*16 + agrp*4;
#pragma unroll
    for (int n = 0; n < 4; n++){
      int col = wc*64 + n*16 + arow;
#pragma unroll
      for (int r2 = 0; r2 < 4; r2++){
        int row = rb0 + r2;
        float v = actf(actid, acc[m][n][r2]);
        Ht[row * 128 + (col ^ ((row & 7) << 3))] = f2bf(v);
      }
    }
  }
  __syncthreads();
  size_t gbase = (size_t)c_offs[e] + (size_t)ct * 128;
#pragma unroll
  for (int i = 0; i < 8; i++){
    int c = tid + i * 256;
    int row = c >> 4, chunk = c & 15;
    int schunk = (chunk & 8) | ((chunk ^ row) & 7);
    int4 val = *(const int4*)&Ht[row * 128 + schunk * 8];
    *(int4*)&HH[(size_t)(rowBase + row) * DSUM + gbase + chunk * 8] = val;
  }
}

// ---------------- expert down-proj + LN + gated accumulate (skip gate==0) ------
__global__ __launch_bounds__(256)
void expert_down(const uint16_t* __restrict__ HH, const float* __restrict__ ED,
                 const float* __restrict__ sg, const float* __restrict__ eng,
                 const float* __restrict__ enb, float* __restrict__ EL)
{
  int lane = threadIdx.x & 63;
  int row = blockIdx.x * 4 + (threadIdx.x >> 6);
  float out[10] = {};
  for (int e = 0; e < NEXP; e++){
    float g = sg[row * 10 + e];
    if (g != 0.0f){
      int d = c_dims[e];
      const uint16_t* hr = HH + (size_t)row * DSUM + c_offs[e];
      const float* wd = ED + (size_t)e * 10 * DMAX;
      float p[10] = {};
      for (int k = lane * 2; k < d; k += 128){
        uint32_t hv2 = *(const uint32_t*)&hr[k];
        float h0 = bf2f((uint16_t)hv2), h1 = bf2f((uint16_t)(hv2 >> 16));
#pragma unroll
        for (int o = 0; o < 10; o++){
          float2 w2 = *(const float2*)&wd[o * DMAX + k];
          p[o] = fmaf(h0, w2.x, fmaf(h1, w2.y, p[o]));
        }
      }
#pragma unroll
      for (int o = 0; o < 10; o++) p[o] = wred(p[o]);
      float mean = 0.f;
#pragma unroll
      for (int o = 0; o < 10; o++) mean += p[o];
      mean *= 0.1f;
      float var = 0.f;
#pragma unroll
      for (int o = 0; o < 10; o++){ float dd = p[o] - mean; var += dd * dd; }
      var *= 0.1f;
      float rs = 1.f / sqrtf(var + 1e-5f);
#pragma unroll
      for (int o = 0; o < 10; o++)
        out[o] += g * ((p[o] - mean) * rs * eng[e * 10 + o] + enb[e * 10 + o]);
    }
  }
  if (lane == 0){
#pragma unroll
    for (int o = 0; o < 10; o++) EL[row * 10 + o] = out[o];
  }
}

// ---------------- memory attention: softmax(mq@keys^T/32) -> u, s_tau ---------
__global__ __launch_bounds__(256)
void mem_attn_kernel(const float* __restrict__ mq, const float* __restrict__ keys,
                     const float* __restrict__ Ac, const float* __restrict__ W0,
                     const float* __restrict__ W1, const float* __restrict__ W2,
                     float* __restrict__ ubuf, float* __restrict__ sval, int t)
{
  int lane = threadIdx.x & 63;
  int row = blockIdx.x * 4 + (threadIdx.x >> 6);
  size_t rb = (size_t)row * IN_D;
  float p[24];
#pragma unroll
  for (int m = 0; m < 24; m++) p[m] = 0.f;
  for (int k = lane; k < IN_D; k += 64){
    float qv = mq[rb + k];
#pragma unroll
    for (int m = 0; m < 24; m++) p[m] = fmaf(qv, keys[m * IN_D + k], p[m]);
  }
#pragma unroll
  for (int m = 0; m < 24; m++) p[m] = wred(p[m]) * 0.03125f;
  float mx = p[0];
#pragma unroll
  for (int m = 1; m < 24; m++) mx = fmaxf(mx, p[m]);
  float s = 0.f;
#pragma unroll
  for (int m = 0; m < 24; m++){ p[m] = expf(p[m] - mx); s += p[m]; }
  float inv = 1.f / s;
  float s0 = 0.f, s1 = 0.f, s2 = 0.f;
#pragma unroll
  for (int m = 0; m < 24; m++){
    float a = p[m] * inv;
    p[m] = a;
    if (t > 0) s0 = fmaf(a, W0[row * 24 + m], s0);
    if (t > 1) s1 = fmaf(a, W1[row * 24 + m], s1);
    if (t > 2) s2 = fmaf(a, W2[row * 24 + m], s2);
  }
  if (lane == 0){
#pragma unroll
    for (int m = 0; m < 24; m++) ubuf[row * 24 + m] = p[m] * Ac[row * 24 + m];
    sval[row * 4 + 0] = s0; sval[row * 4 + 1] = s1; sval[row * 4 + 2] = s2;
  }
}

// ---------------- mem_ctx = u @ init + sum_tau s_tau * wv_tau ------------------
__global__ __launch_bounds__(256)
void mem_ctx_kernel(const float* __restrict__ ubuf, const float* __restrict__ mvi,
                    const float* __restrict__ sval, const float* __restrict__ wv0,
                    const float* __restrict__ wv1, const float* __restrict__ wv2,
                    float* __restrict__ mctx, int t)
{
  int row = blockIdx.x;
  int tid = threadIdx.x;
  __shared__ float su[24];
  __shared__ float ss[3];
  if (tid < 24) su[tid] = ubuf[row * 24 + tid];
  if (tid >= 32 && tid < 35) ss[tid - 32] = sval[row * 4 + (tid - 32)];
  __syncthreads();
  for (int d = tid; d < IN_D; d += 256){
    float v = 0.f;
#pragma unroll
    for (int m = 0; m < 24; m++) v = fmaf(su[m], mvi[m * IN_D + d], v);
    size_t idx = (size_t)row * IN_D + d;
    if (t > 0) v = fmaf(ss[0], wv0[idx], v);
    if (t > 1) v = fmaf(ss[1], wv1[idx], v);
    if (t > 2) v = fmaf(ss[2], wv2[idx], v);
    mctx[idx] = v;
  }
}

// ---------------- depth attention over <=3 cached bank items -------------------
__global__ __launch_bounds__(256)
void depth_kernel(const float* __restrict__ q, const float* __restrict__ k0p,
                  const float* __restrict__ k1p, const float* __restrict__ k2p,
                  const float* __restrict__ v0p, const float* __restrict__ v1p,
                  const float* __restrict__ v2p, float* __restrict__ dctx, int t)
{
  int lane = threadIdx.x & 63;
  int row = blockIdx.x * 4 + (threadIdx.x >> 6);
  size_t rb = (size_t)row * IN_D;
  float a0 = 0.f, a1 = 0.f, a2 = 0.f;
  for (int k = lane; k < IN_D; k += 64){
    float qv = q[rb + k];
    a0 = fmaf(qv, k0p[rb + k], a0);
    if (t > 1) a1 = fmaf(qv, k1p[rb + k], a1);
    if (t > 2) a2 = fmaf(qv, k2p[rb + k], a2);
  }
  a0 = wred(a0) * 0.03125f; a1 = wred(a1) * 0.03125f; a2 = wred(a2) * 0.03125f;
  float mx = a0;
  if (t > 1) mx = fmaxf(mx, a1);
  if (t > 2) mx = fmaxf(mx, a2);
  float e0 = expf(a0 - mx);
  float e1 = (t > 1) ? expf(a1 - mx) : 0.f;
  float e2 = (t > 2) ? expf(a2 - mx) : 0.f;
  float inv = 1.f / (e0 + e1 + e2);
  e0 *= inv; e1 *= inv; e2 *= inv;
  for (int k = lane; k < IN_D; k += 64){
    float v = e0 * v0p[rb + k];
    if (t > 1) v = fmaf(e1, v1p[rb + k], v);
    if (t > 2) v = fmaf(e2, v2p[rb + k], v);
    dctx[rb + k] = v;
  }
}

// ---------------- ssm first stage: tanh(cur @ ssm_a_w^T + b) -------------------
__global__ __launch_bounds__(256)
void ssm_a_kernel(const float* __restrict__ cur, const float* __restrict__ saw,
                  const float* __restrict__ sab, float* __restrict__ t40)
{
  int lane = threadIdx.x & 63;
  int row = blockIdx.x * 4 + (threadIdx.x >> 6);
  size_t rb = (size_t)row * IN_D;
  float p[40];
#pragma unroll
  for (int o = 0; o < 40; o++) p[o] = 0.f;
  for (int k = lane; k < IN_D; k += 64){
    float cv = cur[rb + k];
#pragma unroll
    for (int o = 0; o < 40; o++) p[o] = fmaf(cv, saw[o * IN_D + k], p[o]);
  }
#pragma unroll
  for (int o = 0; o < 40; o++) p[o] = wred(p[o]);
  if (lane == 0){
#pragma unroll
    for (int o = 0; o < 40; o++) t40[row * 40 + o] = tanhf(p[o] + sab[o]);
  }
}

// ---------------- enriched + LN (fuses ssm second stage) -----------------------
__global__ __launch_bounds__(256)
void enriched_kernel(const float* __restrict__ cur, const float* __restrict__ mctx,
                     const float* __restrict__ dctx, const float* __restrict__ t40,
                     const float* __restrict__ sbw, const float* __restrict__ sbb,
                     const float* __restrict__ lng, const float* __restrict__ lnbv,
                     float* __restrict__ enr, float* __restrict__ lnout, int t)
{
  int row = blockIdx.x;
  int tid = threadIdx.x;
  __shared__ float s40[40];
  __shared__ float red[8];
  if (tid < 40) s40[tid] = t40[row * 40 + tid];
  __syncthreads();
  float ev[4];
  float part = 0.f;
#pragma unroll
  for (int j = 0; j < 4; j++){
    int d = tid + j * 256;
    float sv = sbb[d];
#pragma unroll
    for (int o = 0; o < 40; o++) sv = fmaf(s40[o], sbw[d * 40 + o], sv);
    size_t idx = (size_t)row * IN_D + d;
    float v = cur[idx] + 0.34f * mctx[idx] + 0.22f * dctx[idx] + 0.18f * sv;
    ev[j] = v; part += v;
  }
  part = wred(part);
  if ((tid & 63) == 0) red[tid >> 6] = part;
  __syncthreads();
  float mean = (red[0] + red[1] + red[2] + red[3]) * (1.f / 1024.f);
  float vp = 0.f;
#pragma unroll
  for (int j = 0; j < 4; j++){ float dd = ev[j] - mean; vp += dd * dd; }
  vp = wred(vp);
  if ((tid & 63) == 0) red[4 + (tid >> 6)] = vp;
  __syncthreads();
  float var = (red[4] + red[5] + red[6] + red[7]) * (1.f / 1024.f);
  float rs = 1.f / sqrtf(var + 1e-5f);
#pragma unroll
  for (int j = 0; j < 4; j++){
    int d = tid + j * 256;
    size_t idx = (size_t)row * IN_D + d;
    enr[idx] = ev[j];
    lnout[idx] = (ev[j] - mean) * rs * lng[t * IN_D + d] + lnbv[t * IN_D + d];
  }
}

// ---------------- routing: gates, budget, top-k, wg, halt, coeff update --------
__global__ __launch_bounds__(256)
void routing_kernel(const float* __restrict__ cur, const float* __restrict__ mctx,
                    const float* __restrict__ dctx,
                    const float* __restrict__ msw, const float* __restrict__ msb,
                    const float* __restrict__ mmw, const float* __restrict__ mmb,
                    const float* __restrict__ ebias,
                    const float* __restrict__ bw, const float* __restrict__ bb,
                    const float* __restrict__ wgw, const float* __restrict__ wgb,
                    const float* __restrict__ hw, const float* __restrict__ hb,
                    float* __restrict__ sg, float* __restrict__ haltb,
                    float* __restrict__ Ac, float* __restrict__ W0,
                    float* __restrict__ W1, float* __restrict__ W2, int t)
{
  int lane = threadIdx.x & 63;
  int row = blockIdx.x * 4 + (threadIdx.x >> 6);
  size_t rb = (size_t)row * IN_D;
  float ps[40], pw[24], pm[4], pb[4], ph = 0.f;
#pragma unroll
  for (int o = 0; o < 40; o++) ps[o] = 0.f;
#pragma unroll
  for (int m = 0; m < 24; m++) pw[m] = 0.f;
#pragma unroll
  for (int o = 0; o < 4; o++){ pm[o] = 0.f; pb[o] = 0.f; }
  const float* hwt = hw + t * IN_D;
  for (int k = lane; k < IN_D; k += 64){
    float cv = cur[rb + k], mv = mctx[rb + k], dv = dctx[rb + k];
#pragma unroll
    for (int o = 0; o < 40; o++) ps[o] = fmaf(cv, msw[o * IN_D + k], ps[o]);
#pragma unroll
    for (int o = 0; o < 4; o++) pm[o] = fmaf(cv, mmw[o * IN_D + k], pm[o]);
#pragma unroll
    for (int o = 0; o < 4; o++) pb[o] = fmaf(cv, bw[o * IN_D + k], pb[o]);
#pragma unroll
    for (int m = 0; m < 24; m++){
      float t1 = fmaf(cv, wgw[m * 2048 + k], pw[m]);
      pw[m] = fmaf(mv, wgw[m * 2048 + 1024 + k], t1);
    }
    ph = fmaf(cv + 0.2f * mv + 0.1f * dv, hwt[k], ph);
  }
#pragma unroll
  for (int o = 0; o < 40; o++) ps[o] = wred(ps[o]);
#pragma unroll
  for (int m = 0; m < 24; m++) pw[m] = wred(pw[m]);
#pragma unroll
  for (int o = 0; o < 4; o++){ pm[o] = wred(pm[o]); pb[o] = wred(pb[o]); }
  ph = wred(ph);

#pragma unroll
  for (int o = 0; o < 4; o++) pm[o] += mmb[o];
  float mmx = fmaxf(fmaxf(pm[0], pm[1]), fmaxf(pm[2], pm[3]));
  float msum = 0.f;
#pragma unroll
  for (int o = 0; o < 4; o++){ pm[o] = expf(pm[o] - mmx); msum += pm[o]; }
  float minv = 1.f / msum;
  float gl[10];
#pragma unroll
  for (int e = 0; e < 10; e++){
    float g = ebias[e];
#pragma unroll
    for (int s2 = 0; s2 < 4; s2++) g = fmaf(pm[s2] * minv, ps[s2 * 10 + e] + msb[s2 * 10 + e], g);
    gl[e] = g;
  }
  float gmx = gl[0];
#pragma unroll
  for (int e = 1; e < 10; e++) gmx = fmaxf(gmx, gl[e]);
  float gs = 0.f;
#pragma unroll
  for (int e = 0; e < 10; e++){ gl[e] = expf(gl[e] - gmx); gs += gl[e]; }
  float ginv = 1.f / gs;
#pragma unroll
  for (int e = 0; e < 10; e++) gl[e] *= ginv;
#pragma unroll
  for (int o = 0; o < 4; o++) pb[o] += bb[o];
  int bud = 1; float bbest = pb[0];
  if (pb[1] > bbest){ bbest = pb[1]; bud = 2; }
  if (pb[2] > bbest){ bbest = pb[2]; bud = 3; }
  if (pb[3] > bbest){ bbest = pb[3]; bud = 4; }
  float tv[4]; int ti[4]; unsigned used = 0;
#pragma unroll
  for (int j = 0; j < 4; j++){
    float best = -1e30f; int bi = 0;
#pragma unroll
    for (int e = 0; e < 10; e++){
      bool ok = (!((used >> e) & 1u)) && (gl[e] > best);
      if (ok){ best = gl[e]; bi = e; }
    }
    tv[j] = best; ti[j] = bi; used |= (1u << bi);
  }
  float ssum = tv[0];
  if (bud > 1) ssum += tv[1];
  if (bud > 2) ssum += tv[2];
  if (bud > 3) ssum += tv[3];
  float den = fmaxf(ssum, 1e-6f);
  float sup = 1.f - tv[0] / den;
#pragma unroll
  for (int m = 0; m < 24; m++) pw[m] += wgb[m];
  float wmx = pw[0];
#pragma unroll
  for (int m = 1; m < 24; m++) wmx = fmaxf(wmx, pw[m]);
  float wsum = 0.f;
#pragma unroll
  for (int m = 0; m < 24; m++){ pw[m] = expf(pw[m] - wmx); wsum += pw[m]; }
  float winv = 1.f / wsum;
  float hv = 1.f / (1.f + expf(-(ph + hb[t])));

  if (lane == 0){
#pragma unroll
    for (int e = 0; e < 10; e++){
      float sv = 0.f;
#pragma unroll
      for (int j = 0; j < 4; j++) if (j < bud && ti[j] == e) sv = tv[j] / den;
      sg[row * 10 + e] = sv;
    }
    haltb[row] = hv;
#pragma unroll
    for (int m = 0; m < 24; m++){
      float c = sup * pw[m] * winv;
      float om = 1.f - c;
      Ac[row * 24 + m] *= om;
      if (t > 0) W0[row * 24 + m] *= om;
      if (t > 1) W1[row * 24 + m] *= om;
      if (t > 2) W2[row * 24 + m] *= om;
      if (t == 0)      W0[row * 24 + m] = c;
      else if (t == 1) W1[row * 24 + m] = c;
      else if (t == 2) W2[row * 24 + m] = c;
    }
  }
}

// ---------------- finalize step: total += remaining*step_logits ----------------
__global__ __launch_bounds__(256)
void finalize_kernel(const float* __restrict__ mctx, const float* __restrict__ dctx,
                     const float* __restrict__ mow, const float* __restrict__ dow,
                     const float* __restrict__ EL, const float* __restrict__ haltb,
                     float* __restrict__ total, float* __restrict__ cumh)
{
  int lane = threadIdx.x & 63;
  int row = blockIdx.x * 4 + (threadIdx.x >> 6);
  size_t rb = (size_t)row * IN_D;
  float p1[10], p2[10];
#pragma unroll
  for (int o = 0; o < 10; o++){ p1[o] = 0.f; p2[o] = 0.f; }
  for (int k = lane; k < IN_D; k += 64){
    float mv = mctx[rb + k], dv = dctx[rb + k];
#pragma unroll
    for (int o = 0; o < 10; o++){
      p1[o] = fmaf(mv, mow[o * IN_D + k], p1[o]);
      p2[o] = fmaf(dv, dow[o * IN_D + k], p2[o]);
    }
  }
#pragma unroll
  for (int o = 0; o < 10; o++){ p1[o] = wred(p1[o]); p2[o] = wred(p2[o]); }
  if (lane == 0){
    float rem = 1.f - cumh[row];
#pragma unroll
    for (int o = 0; o < 10; o++)
      total[row * 10 + o] += rem * (EL[row * 10 + o] + 0.22f * p1[o] + 0.14f * p2[o]);
    cumh[row] += rem * haltb[row];
  }
}

// ---------------- base = x@weight^T + bias -------------------------------------
__global__ __launch_bounds__(256)
void base_kernel(const float* __restrict__ x, const float* __restrict__ w,
                 const float* __restrict__ b, float* __restrict__ outp)
{
  int lane = threadIdx.x & 63;
  int row = blockIdx.x * 4 + (threadIdx.x >> 6);
  size_t rb = (size_t)row * IN_D;
  float p[10];
#pragma unroll
  for (int o = 0; o < 10; o++) p[o] = 0.f;
  for (int k = lane; k < IN_D; k += 64){
    float xv = x[rb + k];
#pragma unroll
    for (int o = 0; o < 10; o++) p[o] = fmaf(xv, w[o * IN_D + k], p[o]);
  }
#pragma unroll
  for (int o = 0; o < 10; o++) p[o] = wred(p[o]);
  if (lane == 0){
#pragma unroll
    for (int o = 0; o < 10; o++) outp[row * 10 + o] = p[o] + b[o];
  }
}

// ---------------- shared branch: LN(shared_pre @ sdw^T) ------------------------
__global__ __launch_bounds__(256)
void shared_kernel(const float* __restrict__ shpre, const float* __restrict__ sdw,
                   const float* __restrict__ g, const float* __restrict__ b,
                   float* __restrict__ outp)
{
  int lane = threadIdx.x & 63;
  int row = blockIdx.x * 4 + (threadIdx.x >> 6);
  const float* xr = shpre + (size_t)row * SHD;
  float p[10];
#pragma unroll
  for (int o = 0; o < 10; o++) p[o] = 0.f;
  for (int k = lane; k < SHD; k += 64){
    float xv = xr[k];
#pragma unroll
    for (int o = 0; o < 10; o++) p[o] = fmaf(xv, sdw[o * SHD + k], p[o]);
  }
#pragma unroll
  for (int o = 0; o < 10; o++) p[o] = wred(p[o]);
  float mean = 0.f;
#pragma unroll
  for (int o = 0; o < 10; o++) mean += p[o];
  mean *= 0.1f;
  float var = 0.f;
#pragma unroll
  for (int o = 0; o < 10; o++){ float dd = p[o] - mean; var += dd * dd; }
  var *= 0.1f;
  float rs = 1.f / sqrtf(var + 1e-5f);
  if (lane == 0){
#pragma unroll
    for (int o = 0; o < 10; o++) outp[row * 10 + o] = (p[o] - mean) * rs * g[o] + b[o];
  }
}

// ---------------- final output --------------------------------------------------
__global__ __launch_bounds__(256)
void final_out_kernel(const float* __restrict__ cur, const float* __restrict__ mow,
                      const float* __restrict__ basep, const float* __restrict__ sharedp,
                      const float* __restrict__ total, const float* __restrict__ sscale,
                      const float* __restrict__ alphap, const float* __restrict__ betap,
                      float* __restrict__ outp)
{
  int lane = threadIdx.x & 63;
  int row = blockIdx.x * 4 + (threadIdx.x >> 6);
  size_t rb = (size_t)row * IN_D;
  float p[10];
#pragma unroll
  for (int o = 0; o < 10; o++) p[o] = 0.f;
  for (int k = lane; k < IN_D; k += 64){
    float cv = cur[rb + k];
#pragma unroll
    for (int o = 0; o < 10; o++) p[o] = fmaf(cv, mow[o * IN_D + k], p[o]);
  }
#pragma unroll
  for (int o = 0; o < 10; o++) p[o] = wred(p[o]);
  if (lane == 0){
    float ss = sscale[0], av = alphap[0] + 1e-4f, bv = betap[0];
#pragma unroll
    for (int o = 0; o < 10; o++)
      outp[row * 10 + o] = basep[row * 10 + o] + ss * sharedp[row * 10 + o]
                         + av * (total[row * 10 + o] * 0.25f) + bv * p[o];
  }
}

// ---------------- utility kernels ----------------------------------------------
__global__ void cvt_bf16_kernel(const float* __restrict__ src, uint16_t* __restrict__ dst, size_t n){
  size_t i = ((size_t)blockIdx.x * blockDim.x + threadIdx.x) << 2;
  size_t stride = ((size_t)gridDim.x * blockDim.x) << 2;
  for (; i < n; i += stride){
    float4 v = *(const float4*)(src + i);
    ushort4 h;
    h.x = f2bf(v.x); h.y = f2bf(v.y); h.z = f2bf(v.z); h.w = f2bf(v.w);
    *(ushort4*)(dst + i) = h;
  }
}
__global__ void fill1_kernel(float* __restrict__ p, int n){
  int i = blockIdx.x * blockDim.x + threadIdx.x;
  if (i < n) p[i] = 1.f;
}

// ================================================================================
extern "C" void kernel_launch(void* const* d_in, const int* in_sizes, int n_in,
                              void* d_out, int out_size, void* d_ws, size_t ws_size,
                              hipStream_t stream)
{
  const float* x     = (const float*)d_in[0];
  const float* wgt   = (const float*)d_in[1];
  const float* bias  = (const float*)d_in[2];
  const float* suw   = (const float*)d_in[3];
  const float* sdw   = (const float*)d_in[4];
  const float* sng   = (const float*)d_in[5];
  const float* snb   = (const float*)d_in[6];
  const float* sscale= (const float*)d_in[7];
  const float* keys  = (const float*)d_in[8];
  const float* mvi   = (const float*)d_in[9];
  const float* mqw   = (const float*)d_in[10];
  const float* mow   = (const float*)d_in[11];
  const float* wgw   = (const float*)d_in[12];
  const float* wgb   = (const float*)d_in[13];
  const float* wvw   = (const float*)d_in[14];
  const float* wvb   = (const float*)d_in[15];
  const float* dqw   = (const float*)d_in[16];
  const float* dkw   = (const float*)d_in[17];
  const float* dvw   = (const float*)d_in[18];
  const float* dow   = (const float*)d_in[19];
  const float* clng  = (const float*)d_in[20];
  const float* clnb  = (const float*)d_in[21];
  const float* fc1w  = (const float*)d_in[22];
  const float* fc1b  = (const float*)d_in[23];
  const float* fc2w  = (const float*)d_in[24];
  const float* fc2b  = (const float*)d_in[25];
  const float* saw   = (const float*)d_in[26];
  const float* sab   = (const float*)d_in[27];
  const float* sbw   = (const float*)d_in[28];
  const float* sbb   = (const float*)d_in[29];
  const float* msw   = (const float*)d_in[30];
  const float* msb   = (const float*)d_in[31];
  const float* mmw   = (const float*)d_in[32];
  const float* mmb   = (const float*)d_in[33];
  const float* ebias = (const float*)d_in[34];
  const float* bw    = (const float*)d_in[35];
  const float* bb    = (const float*)d_in[36];
  const float* eup   = (const float*)d_in[37];
  const float* edn   = (const float*)d_in[38];
  const float* eng   = (const float*)d_in[39];
  const float* enb   = (const float*)d_in[40];
  const float* hw    = (const float*)d_in[41];
  const float* hb    = (const float*)d_in[42];
  const float* alphap= (const float*)d_in[43];
  const float* betap = (const float*)d_in[44];
  float* outp = (float*)d_out;

  char* wsb = (char*)d_ws;
  size_t off = 0;
  auto AL = [&](size_t bytes) -> void* {
    void* p = wsb + off;
    off = (off + bytes + 255) & ~(size_t)255;
    return p;
  };
  const size_t NI = (size_t)N_TOK * IN_D;
  float* cur    = (float*)AL(NI * 4);
  float* enr    = (float*)AL(NI * 4);
  float* lnbuf  = (float*)AL(NI * 4);
  float* h768   = (float*)AL((size_t)N_TOK * INNER * 4);
  float* mq     = (float*)AL(NI * 4);              // reused as q
  float* mctx   = (float*)AL(NI * 4);
  float* dctx   = (float*)AL(NI * 4);
  float* t40    = (float*)AL((size_t)N_TOK * 40 * 4);
  float* wv0    = (float*)AL(NI * 4);
  float* wv1    = (float*)AL(NI * 4);
  float* wv2    = (float*)AL(NI * 4);
  float* kc0    = (float*)AL(NI * 4);
  float* kc1    = (float*)AL(NI * 4);
  float* kc2    = (float*)AL(NI * 4);
  float* vc0    = (float*)AL(NI * 4);
  float* vc1    = (float*)AL(NI * 4);
  float* vc2    = (float*)AL(NI * 4);
  float* ubuf   = (float*)AL((size_t)N_TOK * 24 * 4);
  float* sval   = (float*)AL((size_t)N_TOK * 4 * 4);
  float* Ac     = (float*)AL((size_t)N_TOK * 24 * 4);
  float* W0     = (float*)AL((size_t)N_TOK * 24 * 4);
  float* W1     = (float*)AL((size_t)N_TOK * 24 * 4);
  float* W2     = (float*)AL((size_t)N_TOK * 24 * 4);
  float* sg     = (float*)AL((size_t)N_TOK * 10 * 4);
  float* haltb  = (float*)AL((size_t)N_TOK * 4);
  float* EL     = (float*)AL((size_t)N_TOK * 10 * 4);
  float* total  = (float*)AL((size_t)N_TOK * 10 * 4);
  float* cumh   = (float*)AL((size_t)N_TOK * 4);
  float* basep  = (float*)AL((size_t)N_TOK * 10 * 4);
  float* sharedp= (float*)AL((size_t)N_TOK * 10 * 4);
  // bf16 split activation buffers
  uint16_t* curh = (uint16_t*)AL(NI * 2);
  uint16_t* curl = (uint16_t*)AL(NI * 2);
  uint16_t* lnh  = (uint16_t*)AL(NI * 2);
  uint16_t* lnl  = (uint16_t*)AL(NI * 2);
  uint16_t* h7h  = (uint16_t*)AL((size_t)N_TOK * INNER * 2);
  uint16_t* h7l  = (uint16_t*)AL((size_t)N_TOK * INNER * 2);
  // bf16 split weights
  const size_t W1M = (size_t)IN_D * IN_D;
  uint16_t* mqwh = (uint16_t*)AL(W1M * 2); uint16_t* mqwl = (uint16_t*)AL(W1M * 2);
  uint16_t* dqwh = (uint16_t*)AL(W1M * 2); uint16_t* dqwl = (uint16_t*)AL(W1M * 2);
  uint16_t* dkwh = (uint16_t*)AL(W1M * 2); uint16_t* dkwl = (uint16_t*)AL(W1M * 2);
  uint16_t* dvwh = (uint16_t*)AL(W1M * 2); uint16_t* dvwl = (uint16_t*)AL(W1M * 2);
  uint16_t* wvwh = (uint16_t*)AL(W1M * 2); uint16_t* wvwl = (uint16_t*)AL(W1M * 2);
  const size_t WFC = (size_t)NSTEP * INNER * IN_D;
  uint16_t* fc1wh = (uint16_t*)AL(WFC * 2); uint16_t* fc1wl = (uint16_t*)AL(WFC * 2);
  uint16_t* fc2wh = (uint16_t*)AL(WFC * 2); uint16_t* fc2wl = (uint16_t*)AL(WFC * 2);
  const size_t WSU = (size_t)SHD * IN_D;
  uint16_t* suwh = (uint16_t*)AL(WSU * 2); uint16_t* suwl = (uint16_t*)AL(WSU * 2);
  // big buffers
  uint16_t* upbf  = (uint16_t*)AL((size_t)NEXP * DMAX * IN_D * 2);
  uint16_t* hh    = (uint16_t*)AL((size_t)N_TOK * DSUM * 2);
  float* shpre  = (float*)hh;   // alias: shpre consumed before hh is written

  // ---- init (re-done every launch: deterministic) ----
  hipMemsetAsync(dctx, 0, NI * 4, stream);
  hipMemsetAsync(total, 0, (size_t)N_TOK * 10 * 4, stream);
  hipMemsetAsync(cumh, 0, (size_t)N_TOK * 4, stream);
  hipMemcpyAsync(cur, x, NI * 4, hipMemcpyDeviceToDevice, stream);
  fill1_kernel<<<(N_TOK * 24 + 255) / 256, 256, 0, stream>>>(Ac, N_TOK * 24);
  cvt_bf16_kernel<<<2048, 256, 0, stream>>>(eup, upbf, (size_t)NEXP * DMAX * IN_D);
  // weight splits (cheap: ~107 MB traffic total)
  split_kernel<<<1024, 256, 0, stream>>>(mqw, mqwh, mqwl, W1M);
  split_kernel<<<1024, 256, 0, stream>>>(dqw, dqwh, dqwl, W1M);
  split_kernel<<<1024, 256, 0, stream>>>(dkw, dkwh, dkwl, W1M);
  split_kernel<<<1024, 256, 0, stream>>>(dvw, dvwh, dvwl, W1M);
  split_kernel<<<1024, 256, 0, stream>>>(wvw, wvwh, wvwl, W1M);
  split_kernel<<<1024, 256, 0, stream>>>(fc1w, fc1wh, fc1wl, WFC);
  split_kernel<<<1024, 256, 0, stream>>>(fc2w, fc2wh, fc2wl, WFC);
  split_kernel<<<1024, 256, 0, stream>>>(suw, suwh, suwl, WSU);
  split_kernel<<<1024, 256, 0, stream>>>(x, curh, curl, NI);

  base_kernel<<<512, 256, 0, stream>>>(x, wgt, bias, basep);
  gemm_sp<EPI_SILU><<<dim3(SHD/128, N_TOK/128), 256, 0, stream>>>(
      curh, curl, suwh, suwl, nullptr, nullptr, shpre, IN_D, SHD);
  shared_kernel<<<512, 256, 0, stream>>>(shpre, sdw, sng, snb, sharedp);

  float* wvB[3] = {wv0, wv1, wv2};
  float* kcB[3] = {kc0, kc1, kc2};
  float* vcB[3] = {vc0, vc1, vc2};

  for (int t = 0; t < NSTEP; t++){
    // memory attention path (curh/curl hold split of current `cur`)
    gemm_sp<EPI_NONE><<<dim3(8, 16), 256, 0, stream>>>(
        curh, curl, mqwh, mqwl, nullptr, nullptr, mq, IN_D, IN_D);
    mem_attn_kernel<<<512, 256, 0, stream>>>(mq, keys, Ac, W0, W1, W2, ubuf, sval, t);
    mem_ctx_kernel<<<2048, 256, 0, stream>>>(ubuf, mvi, sval, wv0, wv1, wv2, mctx, t);
    // depth attention path
    if (t > 0){
      gemm_sp<EPI_NONE><<<dim3(8, 16), 256, 0, stream>>>(
          curh, curl, dqwh, dqwl, nullptr, nullptr, mq, IN_D, IN_D);
      depth_kernel<<<512, 256, 0, stream>>>(mq, kc0, kc1, kc2, vc0, vc1, vc2, dctx, t);
    }
    // ssm + enriched + LN
    ssm_a_kernel<<<512, 256, 0, stream>>>(cur, saw, sab, t40);
    enriched_kernel<<<2048, 256, 0, stream>>>(cur, mctx, dctx, t40, sbw, sbb, clng, clnb, enr, lnbuf, t);
    // cell MLP
    split_kernel<<<1024, 256, 0, stream>>>(lnbuf, lnh, lnl, NI);
    gemm_sp<EPI_GELU_BIAS><<<dim3(INNER/128, 16), 256, 0, stream>>>(
        lnh, lnl, fc1wh + (size_t)t * INNER * IN_D, fc1wl + (size_t)t * INNER * IN_D,
        fc1b + t * INNER, nullptr, h768, IN_D, INNER);
    split_kernel<<<1024, 256, 0, stream>>>(h768, h7h, h7l, (size_t)N_TOK * INNER);
    gemm_sp<EPI_ADD_BIAS><<<dim3(8, 16), 256, 0, stream>>>(
        h7h, h7l, fc2wh + (size_t)t * IN_D * INNER, fc2wl + (size_t)t * IN_D * INNER,
        fc2b + t * IN_D, enr, cur, INNER, IN_D);
    // split new cur (hi part doubles as the expert bf16 input)
    split_kernel<<<1024, 256, 0, stream>>>(cur, curh, curl, NI);
    // bank projections + wv for future steps
    if (t < 3){
      gemm_sp<EPI_NONE><<<dim3(8, 16), 256, 0, stream>>>(
          curh, curl, dkwh, dkwl, nullptr, nullptr, kcB[t], IN_D, IN_D);
      gemm_sp<EPI_NONE><<<dim3(8, 16), 256, 0, stream>>>(
          curh, curl, dvwh, dvwl, nullptr, nullptr, vcB[t], IN_D, IN_D);
      gemm_sp<EPI_BIAS><<<dim3(8, 16), 256, 0, stream>>>(
          curh, curl, wvwh, wvwl, wvb, nullptr, wvB[t], IN_D, IN_D);
    }
    // routing / gates / coeff update
    routing_kernel<<<512, 256, 0, stream>>>(cur, mctx, dctx, msw, msb, mmw, mmb, ebias,
                                            bw, bb, wgw, wgb, hw, hb,
                                            sg, haltb, Ac, W0, W1, W2, t);
    // experts
    expert_up_mfma<<<dim3(16, 26, 10), 256, 0, stream>>>(curh, upbf, hh);
    expert_down<<<512, 256, 0, stream>>>(hh, edn, sg, eng, enb, EL);
    // accumulate step logits
    finalize_kernel<<<512, 256, 0, stream>>>(mctx, dctx, mow, dow, EL, haltb, total, cumh);
  }
  final_out_kernel<<<512, 256, 0, stream>>>(cur, mow, basep, sharedp, total, sscale,
                                            alphap, betap, outp);
}

// Round 3
// 4408.926 us; speedup vs baseline: 1.9582x; 1.1012x over previous
//
#include <hip/hip_runtime.h>
#include <stdint.h>

#define N_TOK 2048
#define IN_D  1024
#define OUT_D 10
#define NEXP  10
#define MMEM  24
#define NSTEP 4
#define INNER 768
#define SHD   2048
#define DMAX  3328
#define DSUM  24064

typedef __attribute__((ext_vector_type(4))) float f32x4;
typedef __attribute__((ext_vector_type(8))) short bf16x8;

__device__ const int c_dims[10] = {1536,2048,2560,3072,1792,2304,2816,2048,2560,3328};
__device__ const int c_offs[10] = {0,1536,3584,6144,9216,11008,13312,16128,18176,20736};
__device__ const int c_acts[10] = {0,1,2,3,4,5,6,7,0,1};

__device__ __forceinline__ float wred(float v){
#pragma unroll
  for (int s = 32; s > 0; s >>= 1) v += __shfl_xor(v, s, 64);
  return v;
}
__device__ __forceinline__ float bf2f(uint16_t u){
  return __uint_as_float(((uint32_t)u) << 16);
}
__device__ __forceinline__ uint16_t f2bf(float f){
  uint32_t u = __float_as_uint(f);
  return (uint16_t)((u + 0x7FFFu + ((u >> 16) & 1u)) >> 16);
}
__device__ __forceinline__ void gload16(const uint16_t* g, uint16_t* l){
  __builtin_amdgcn_global_load_lds(
      (const __attribute__((address_space(1))) uint32_t*)(const void*)g,
      (__attribute__((address_space(3))) uint32_t*)(void*)l, 16, 0, 0);
}

__device__ __forceinline__ float actf(int a, float x){
  switch(a){
    case 0: return x / (1.f + expf(-x));
    case 1: return 0.5f * x * (1.f + erff(x * 0.7071067811865475f));
    case 2: { float sp = fmaxf(x,0.f) + log1pf(expf(-fabsf(x)));
              return x * tanhf(sp); }
    case 3: return fmaxf(x, 0.f);
    case 4: return x > 0.f ? 1.0507009873554805f * x
                           : 1.7580993408473768f * expm1f(x);
    case 5: return tanhf(x);
    case 6: return fmaxf(x,0.f) + log1pf(expf(-fabsf(x)));
    default: return x > 0.f ? x : expm1f(x);
  }
}

// ---------------- f32 -> (hi, lo) bf16 split -----------------------------------
__global__ void split_kernel(const float* __restrict__ src, uint16_t* __restrict__ hi,
                             uint16_t* __restrict__ lo, size_t n){
  size_t i = ((size_t)blockIdx.x * blockDim.x + threadIdx.x) << 2;
  size_t stride = ((size_t)gridDim.x * blockDim.x) << 2;
  for (; i < n; i += stride){
    float4 v = *(const float4*)(src + i);
    ushort4 h, l;
    h.x = f2bf(v.x); l.x = f2bf(v.x - bf2f(h.x));
    h.y = f2bf(v.y); l.y = f2bf(v.y - bf2f(h.y));
    h.z = f2bf(v.z); l.z = f2bf(v.z - bf2f(h.z));
    h.w = f2bf(v.w); l.w = f2bf(v.w - bf2f(h.w));
    *(ushort4*)(hi + i) = h;
    *(ushort4*)(lo + i) = l;
  }
}

// ---------------- split-bf16 MFMA GEMM: C = epi(A @ W^T), ~f32 precision -------
enum { EPI_NONE=0, EPI_BIAS=1, EPI_GELU_BIAS=2, EPI_ADD_BIAS=3, EPI_SILU=4 };

template<int EPI>
__global__ __launch_bounds__(256)
void gemm_sp(const uint16_t* __restrict__ Ah, const uint16_t* __restrict__ Al,
             const uint16_t* __restrict__ Wh, const uint16_t* __restrict__ Wl,
             const float* __restrict__ bias, const float* __restrict__ addend,
             float* __restrict__ C, uint16_t* __restrict__ outH,
             uint16_t* __restrict__ outL, int K, int D)
{
  __shared__ __align__(16) uint16_t sAh[128*32];
  __shared__ __align__(16) uint16_t sAl[128*32];
  __shared__ __align__(16) uint16_t sWh[128*32];
  __shared__ __align__(16) uint16_t sWl[128*32];
  int tid = threadIdx.x, lane = tid & 63, wave = tid >> 6;
  int wr = wave >> 1, wc = wave & 1;
  int arow = lane & 15, agrp = lane >> 4;
  int rowBase = blockIdx.y * 128, colBase = blockIdx.x * 128;
  f32x4 acc[4][4];
#pragma unroll
  for (int m = 0; m < 4; m++)
#pragma unroll
    for (int n = 0; n < 4; n++){ f32x4 z = {0.f,0.f,0.f,0.f}; acc[m][n] = z; }

  for (int k0 = 0; k0 < K; k0 += 32){
#pragma unroll
    for (int s = 0; s < 2; s++){
      int c = tid + s * 256;
      int rr = c >> 2, cc = (c & 3) << 3;
      size_t ga = (size_t)(rowBase + rr) * K + k0 + cc;
      size_t gw = (size_t)(colBase + rr) * K + k0 + cc;
      gload16(&Ah[ga], &sAh[c << 3]);
      gload16(&Al[ga], &sAl[c << 3]);
      gload16(&Wh[gw], &sWh[c << 3]);
      gload16(&Wl[gw], &sWl[c << 3]);
    }
    __syncthreads();
    bf16x8 ah[4], al[4], bh[4], bl[4];
#pragma unroll
    for (int m = 0; m < 4; m++){
      int ro = (wr*64 + m*16 + arow) * 32 + agrp * 8;
      ah[m] = *(const bf16x8*)&sAh[ro];
      al[m] = *(const bf16x8*)&sAl[ro];
    }
#pragma unroll
    for (int n = 0; n < 4; n++){
      int ro = (wc*64 + n*16 + arow) * 32 + agrp * 8;
      bh[n] = *(const bf16x8*)&sWh[ro];
      bl[n] = *(const bf16x8*)&sWl[ro];
    }
#pragma unroll
    for (int m = 0; m < 4; m++)
#pragma unroll
      for (int n = 0; n < 4; n++){
        acc[m][n] = __builtin_amdgcn_mfma_f32_16x16x32_bf16(ah[m], bh[n], acc[m][n], 0, 0, 0);
        acc[m][n] = __builtin_amdgcn_mfma_f32_16x16x32_bf16(ah[m], bl[n], acc[m][n], 0, 0, 0);
        acc[m][n] = __builtin_amdgcn_mfma_f32_16x16x32_bf16(al[m], bh[n], acc[m][n], 0, 0, 0);
      }
    __syncthreads();
  }
#pragma unroll
  for (int m = 0; m < 4; m++){
#pragma unroll
    for (int n = 0; n < 4; n++){
      int col = colBase + wc*64 + n*16 + arow;
#pragma unroll
      for (int r2 = 0; r2 < 4; r2++){
        int row = rowBase + wr*64 + m*16 + agrp*4 + r2;
        float v = acc[m][n][r2];
        if (EPI == EPI_BIAS || EPI == EPI_GELU_BIAS || EPI == EPI_ADD_BIAS) v += bias[col];
        if (EPI == EPI_GELU_BIAS) v = 0.5f * v * (1.f + erff(v * 0.7071067811865475f));
        if (EPI == EPI_SILU)      v = v / (1.f + expf(-v));
        if (EPI == EPI_ADD_BIAS)  v += addend[(size_t)row * D + col];
        size_t idx = (size_t)row * D + col;
        if (C) C[idx] = v;
        if (outH){
          uint16_t h = f2bf(v);
          outH[idx] = h;
          outL[idx] = f2bf(v - bf2f(h));
        }
      }
    }
  }
}

// ---------------- per-expert token compaction -----------------------------------
__global__ void compact_kernel(const float* __restrict__ sg, int* __restrict__ cnt,
                               int* __restrict__ gidx, int* __restrict__ pos){
  int row = blockIdx.x * 256 + threadIdx.x;
  if (row >= N_TOK) return;
#pragma unroll
  for (int e = 0; e < NEXP; e++){
    if (sg[row * 10 + e] != 0.0f){
      int slot = atomicAdd(&cnt[e], 1);
      gidx[e * N_TOK + slot] = row;
      pos[row * 10 + e] = slot;
    }
  }
}

// ---------------- sparse expert up-projection, bf16 MFMA, BK=64 ----------------
// HHc layout: per expert e, base = 2048*c_offs[e], row stride d_e (compact slots)
__global__ __launch_bounds__(256)
void expert_up_mfma(const uint16_t* __restrict__ Abf, const uint16_t* __restrict__ Ubf,
                    const int* __restrict__ cnt, const int* __restrict__ gidx,
                    uint16_t* __restrict__ HH)
{
  int e = blockIdx.z;
  int dcols = c_dims[e];
  int ct = blockIdx.y;
  if (ct * 128 >= dcols) return;
  int ne = cnt[e];
  int rowBase = blockIdx.x * 128;
  if (rowBase >= ne) return;
  const uint16_t* W = Ubf + (size_t)e * DMAX * IN_D + (size_t)ct * 128 * IN_D;
  __shared__ __align__(16) uint16_t smem[16384];   // As(16KB)|Bs(16KB), reused as Ht
  uint16_t* As = smem;
  uint16_t* Bs = smem + 8192;
  int tid = threadIdx.x, lane = tid & 63, wave = tid >> 6;
  int wr = wave >> 1, wc = wave & 1;
  int arow = lane & 15, agrp = lane >> 4;
  // per-thread gathered token for its 4 staged rows (rows rr = tid>>3 + 32*s)
  int tokA[4];
#pragma unroll
  for (int s = 0; s < 4; s++){
    int rr = (tid + s * 256) >> 3;
    int slot = rowBase + rr;
    tokA[s] = (slot < ne) ? gidx[e * N_TOK + slot] : 0;
  }
  f32x4 acc[4][4];
#pragma unroll
  for (int m = 0; m < 4; m++)
#pragma unroll
    for (int n = 0; n < 4; n++){ f32x4 z = {0.f,0.f,0.f,0.f}; acc[m][n] = z; }

  for (int k0 = 0; k0 < IN_D; k0 += 64){
#pragma unroll
    for (int s = 0; s < 4; s++){
      int c = tid + s * 256;
      int rr = c >> 3, q = c & 7;
      int cc = (q ^ (rr & 7)) << 3;      // pre-swizzled source chunk
      gload16(&Abf[(size_t)tokA[s] * IN_D + k0 + cc], &As[c << 3]);
      gload16(&W[(size_t)rr * IN_D + k0 + cc], &Bs[c << 3]);
    }
    __syncthreads();
#pragma unroll
    for (int kk = 0; kk < 2; kk++){
      bf16x8 a[4], b[4];
#pragma unroll
      for (int m = 0; m < 4; m++){
        int row = wr*64 + m*16 + arow;
        a[m] = *(const bf16x8*)&As[row*64 + (((kk<<2)+agrp) ^ (row&7))*8];
      }
#pragma unroll
      for (int n = 0; n < 4; n++){
        int row = wc*64 + n*16 + arow;
        b[n] = *(const bf16x8*)&Bs[row*64 + (((kk<<2)+agrp) ^ (row&7))*8];
      }
#pragma unroll
      for (int m = 0; m < 4; m++)
#pragma unroll
        for (int n = 0; n < 4; n++)
          acc[m][n] = __builtin_amdgcn_mfma_f32_16x16x32_bf16(a[m], b[n], acc[m][n], 0, 0, 0);
    }
    __syncthreads();
  }
  // epilogue: activation -> swizzled LDS tile -> coalesced 16B stores
  int actid = c_acts[e];
  uint16_t* Ht = smem;
#pragma unroll
  for (int m = 0; m < 4; m++){
    int rb0 = wr*64 + m*16 + agrp*4;
#pragma unroll
    for (int n = 0; n < 4; n++){
      int col = wc*64 + n*16 + arow;
#pragma unroll
      for (int r2 = 0; r2 < 4; r2++){
        int row = rb0 + r2;
        float v = actf(actid, acc[m][n][r2]);
        Ht[row * 128 + (col ^ ((row & 7) << 3))] = f2bf(v);
      }
    }
  }
  __syncthreads();
  size_t base_e = (size_t)N_TOK * c_offs[e];
#pragma unroll
  for (int i = 0; i < 8; i++){
    int c = tid + i * 256;
    int row = c >> 4, chunk = c & 15;
    int schunk = (chunk & 8) | ((chunk ^ row) & 7);
    int4 val = *(const int4*)&Ht[row * 128 + schunk * 8];
    *(int4*)&HH[base_e + (size_t)(rowBase + row) * dcols + (size_t)ct * 128 + chunk * 8] = val;
  }
}

// ---------------- expert down-proj + LN + gated accumulate ---------------------
__global__ __launch_bounds__(256)
void expert_down(const uint16_t* __restrict__ HH, const int* __restrict__ pos,
                 const float* __restrict__ ED, const float* __restrict__ sg,
                 const float* __restrict__ eng, const float* __restrict__ enb,
                 float* __restrict__ EL)
{
  int lane = threadIdx.x & 63;
  int row = blockIdx.x * 4 + (threadIdx.x >> 6);
  float out[10] = {};
  for (int e = 0; e < NEXP; e++){
    float g = sg[row * 10 + e];
    if (g != 0.0f){
      int d = c_dims[e];
      int slot = pos[row * 10 + e];
      const uint16_t* hr = HH + (size_t)N_TOK * c_offs[e] + (size_t)slot * d;
      const float* wd = ED + (size_t)e * 10 * DMAX;
      float p[10] = {};
      for (int k = lane * 2; k < d; k += 128){
        uint32_t hv2 = *(const uint32_t*)&hr[k];
        float h0 = bf2f((uint16_t)hv2), h1 = bf2f((uint16_t)(hv2 >> 16));
#pragma unroll
        for (int o = 0; o < 10; o++){
          float2 w2 = *(const float2*)&wd[o * DMAX + k];
          p[o] = fmaf(h0, w2.x, fmaf(h1, w2.y, p[o]));
        }
      }
#pragma unroll
      for (int o = 0; o < 10; o++) p[o] = wred(p[o]);
      float mean = 0.f;
#pragma unroll
      for (int o = 0; o < 10; o++) mean += p[o];
      mean *= 0.1f;
      float var = 0.f;
#pragma unroll
      for (int o = 0; o < 10; o++){ float dd = p[o] - mean; var += dd * dd; }
      var *= 0.1f;
      float rs = 1.f / sqrtf(var + 1e-5f);
#pragma unroll
      for (int o = 0; o < 10; o++)
        out[o] += g * ((p[o] - mean) * rs * eng[e * 10 + o] + enb[e * 10 + o]);
    }
  }
  if (lane == 0){
#pragma unroll
    for (int o = 0; o < 10; o++) EL[row * 10 + o] = out[o];
  }
}

// ---------------- memory attention ---------------------------------------------
__global__ __launch_bounds__(256)
void mem_attn_kernel(const float* __restrict__ mq, int qs, const float* __restrict__ keys,
                     const float* __restrict__ Ac, const float* __restrict__ W0,
                     const float* __restrict__ W1, const float* __restrict__ W2,
                     float* __restrict__ ubuf, float* __restrict__ sval, int t)
{
  int lane = threadIdx.x & 63;
  int row = blockIdx.x * 4 + (threadIdx.x >> 6);
  size_t rb = (size_t)row * qs;
  float p[24];
#pragma unroll
  for (int m = 0; m < 24; m++) p[m] = 0.f;
  for (int k = lane; k < IN_D; k += 64){
    float qv = mq[rb + k];
#pragma unroll
    for (int m = 0; m < 24; m++) p[m] = fmaf(qv, keys[m * IN_D + k], p[m]);
  }
#pragma unroll
  for (int m = 0; m < 24; m++) p[m] = wred(p[m]) * 0.03125f;
  float mx = p[0];
#pragma unroll
  for (int m = 1; m < 24; m++) mx = fmaxf(mx, p[m]);
  float s = 0.f;
#pragma unroll
  for (int m = 0; m < 24; m++){ p[m] = expf(p[m] - mx); s += p[m]; }
  float inv = 1.f / s;
  float s0 = 0.f, s1 = 0.f, s2 = 0.f;
#pragma unroll
  for (int m = 0; m < 24; m++){
    float a = p[m] * inv;
    p[m] = a;
    if (t > 0) s0 = fmaf(a, W0[row * 24 + m], s0);
    if (t > 1) s1 = fmaf(a, W1[row * 24 + m], s1);
    if (t > 2) s2 = fmaf(a, W2[row * 24 + m], s2);
  }
  if (lane == 0){
#pragma unroll
    for (int m = 0; m < 24; m++) ubuf[row * 24 + m] = p[m] * Ac[row * 24 + m];
    sval[row * 4 + 0] = s0; sval[row * 4 + 1] = s1; sval[row * 4 + 2] = s2;
  }
}

// ---------------- mem_ctx = u @ init + sum_tau s_tau * wv_tau ------------------
// wv_tau lives at trio_tau + 2048, row stride 3072
__global__ __launch_bounds__(256)
void mem_ctx_kernel(const float* __restrict__ ubuf, const float* __restrict__ mvi,
                    const float* __restrict__ sval, const float* __restrict__ t0,
                    const float* __restrict__ t1, const float* __restrict__ t2,
                    float* __restrict__ mctx, int t)
{
  int row = blockIdx.x;
  int tid = threadIdx.x;
  __shared__ float su[24];
  __shared__ float ss[3];
  if (tid < 24) su[tid] = ubuf[row * 24 + tid];
  if (tid >= 32 && tid < 35) ss[tid - 32] = sval[row * 4 + (tid - 32)];
  __syncthreads();
  size_t tb = (size_t)row * 3072 + 2048;
  for (int d = tid; d < IN_D; d += 256){
    float v = 0.f;
#pragma unroll
    for (int m = 0; m < 24; m++) v = fmaf(su[m], mvi[m * IN_D + d], v);
    if (t > 0) v = fmaf(ss[0], t0[tb + d], v);
    if (t > 1) v = fmaf(ss[1], t1[tb + d], v);
    if (t > 2) v = fmaf(ss[2], t2[tb + d], v);
    mctx[(size_t)row * IN_D + d] = v;
  }
}

// ---------------- depth attention (k at trio+0, v at trio+1024, stride 3072) ---
__global__ __launch_bounds__(256)
void depth_kernel(const float* __restrict__ q, int qs, const float* __restrict__ t0,
                  const float* __restrict__ t1, const float* __restrict__ t2,
                  float* __restrict__ dctx, int t)
{
  int lane = threadIdx.x & 63;
  int row = blockIdx.x * 4 + (threadIdx.x >> 6);
  size_t qb = (size_t)row * qs;
  size_t tb = (size_t)row * 3072;
  float a0 = 0.f, a1 = 0.f, a2 = 0.f;
  for (int k = lane; k < IN_D; k += 64){
    float qv = q[qb + k];
    a0 = fmaf(qv, t0[tb + k], a0);
    if (t > 1) a1 = fmaf(qv, t1[tb + k], a1);
    if (t > 2) a2 = fmaf(qv, t2[tb + k], a2);
  }
  a0 = wred(a0) * 0.03125f; a1 = wred(a1) * 0.03125f; a2 = wred(a2) * 0.03125f;
  float mx = a0;
  if (t > 1) mx = fmaxf(mx, a1);
  if (t > 2) mx = fmaxf(mx, a2);
  float e0 = expf(a0 - mx);
  float e1 = (t > 1) ? expf(a1 - mx) : 0.f;
  float e2 = (t > 2) ? expf(a2 - mx) : 0.f;
  float inv = 1.f / (e0 + e1 + e2);
  e0 *= inv; e1 *= inv; e2 *= inv;
  for (int k = lane; k < IN_D; k += 64){
    float v = e0 * t0[tb + 1024 + k];
    if (t > 1) v = fmaf(e1, t1[tb + 1024 + k], v);
    if (t > 2) v = fmaf(e2, t2[tb + 1024 + k], v);
    dctx[(size_t)row * IN_D + k] = v;
  }
}

// ---------------- ssm first stage ----------------------------------------------
__global__ __launch_bounds__(256)
void ssm_a_kernel(const float* __restrict__ cur, const float* __restrict__ saw,
                  const float* __restrict__ sab, float* __restrict__ t40)
{
  int lane = threadIdx.x & 63;
  int row = blockIdx.x * 4 + (threadIdx.x >> 6);
  size_t rb = (size_t)row * IN_D;
  float p[40];
#pragma unroll
  for (int o = 0; o < 40; o++) p[o] = 0.f;
  for (int k = lane; k < IN_D; k += 64){
    float cv = cur[rb + k];
#pragma unroll
    for (int o = 0; o < 40; o++) p[o] = fmaf(cv, saw[o * IN_D + k], p[o]);
  }
#pragma unroll
  for (int o = 0; o < 40; o++) p[o] = wred(p[o]);
  if (lane == 0){
#pragma unroll
    for (int o = 0; o < 40; o++) t40[row * 40 + o] = tanhf(p[o] + sab[o]);
  }
}

// ---------------- enriched + LN, emits bf16 hi/lo of LN output -----------------
__global__ __launch_bounds__(256)
void enriched_kernel(const float* __restrict__ cur, const float* __restrict__ mctx,
                     const float* __restrict__ dctx, const float* __restrict__ t40,
                     const float* __restrict__ sbw, const float* __restrict__ sbb,
                     const float* __restrict__ lng, const float* __restrict__ lnbv,
                     float* __restrict__ enr, uint16_t* __restrict__ lnh,
                     uint16_t* __restrict__ lnl, int t)
{
  int row = blockIdx.x;
  int tid = threadIdx.x;
  __shared__ float s40[40];
  __shared__ float red[8];
  if (tid < 40) s40[tid] = t40[row * 40 + tid];
  __syncthreads();
  float ev[4];
  float part = 0.f;
#pragma unroll
  for (int j = 0; j < 4; j++){
    int d = tid + j * 256;
    float sv = sbb[d];
#pragma unroll
    for (int o = 0; o < 40; o++) sv = fmaf(s40[o], sbw[d * 40 + o], sv);
    size_t idx = (size_t)row * IN_D + d;
    float v = cur[idx] + 0.34f * mctx[idx] + 0.22f * dctx[idx] + 0.18f * sv;
    ev[j] = v; part += v;
  }
  part = wred(part);
  if ((tid & 63) == 0) red[tid >> 6] = part;
  __syncthreads();
  float mean = (red[0] + red[1] + red[2] + red[3]) * (1.f / 1024.f);
  float vp = 0.f;
#pragma unroll
  for (int j = 0; j < 4; j++){ float dd = ev[j] - mean; vp += dd * dd; }
  vp = wred(vp);
  if ((tid & 63) == 0) red[4 + (tid >> 6)] = vp;
  __syncthreads();
  float var = (red[4] + red[5] + red[6] + red[7]) * (1.f / 1024.f);
  float rs = 1.f / sqrtf(var + 1e-5f);
#pragma unroll
  for (int j = 0; j < 4; j++){
    int d = tid + j * 256;
    size_t idx = (size_t)row * IN_D + d;
    enr[idx] = ev[j];
    float v = (ev[j] - mean) * rs * lng[t * IN_D + d] + lnbv[t * IN_D + d];
    uint16_t h = f2bf(v);
    lnh[idx] = h;
    lnl[idx] = f2bf(v - bf2f(h));
  }
}

// ---------------- routing ------------------------------------------------------
__global__ __launch_bounds__(256)
void routing_kernel(const float* __restrict__ cur, const float* __restrict__ mctx,
                    const float* __restrict__ dctx,
                    const float* __restrict__ msw, const float* __restrict__ msb,
                    const float* __restrict__ mmw, const float* __restrict__ mmb,
                    const float* __restrict__ ebias,
                    const float* __restrict__ bw, const float* __restrict__ bb,
                    const float* __restrict__ wgw, const float* __restrict__ wgb,
                    const float* __restrict__ hw, const float* __restrict__ hb,
                    float* __restrict__ sg, float* __restrict__ haltb,
                    float* __restrict__ Ac, float* __restrict__ W0,
                    float* __restrict__ W1, float* __restrict__ W2, int t)
{
  int lane = threadIdx.x & 63;
  int row = blockIdx.x * 4 + (threadIdx.x >> 6);
  size_t rb = (size_t)row * IN_D;
  float ps[40], pw[24], pm[4], pb[4], ph = 0.f;
#pragma unroll
  for (int o = 0; o < 40; o++) ps[o] = 0.f;
#pragma unroll
  for (int m = 0; m < 24; m++) pw[m] = 0.f;
#pragma unroll
  for (int o = 0; o < 4; o++){ pm[o] = 0.f; pb[o] = 0.f; }
  const float* hwt = hw + t * IN_D;
  for (int k = lane; k < IN_D; k += 64){
    float cv = cur[rb + k], mv = mctx[rb + k], dv = dctx[rb + k];
#pragma unroll
    for (int o = 0; o < 40; o++) ps[o] = fmaf(cv, msw[o * IN_D + k], ps[o]);
#pragma unroll
    for (int o = 0; o < 4; o++) pm[o] = fmaf(cv, mmw[o * IN_D + k], pm[o]);
#pragma unroll
    for (int o = 0; o < 4; o++) pb[o] = fmaf(cv, bw[o * IN_D + k], pb[o]);
#pragma unroll
    for (int m = 0; m < 24; m++){
      float t1 = fmaf(cv, wgw[m * 2048 + k], pw[m]);
      pw[m] = fmaf(mv, wgw[m * 2048 + 1024 + k], t1);
    }
    ph = fmaf(cv + 0.2f * mv + 0.1f * dv, hwt[k], ph);
  }
#pragma unroll
  for (int o = 0; o < 40; o++) ps[o] = wred(ps[o]);
#pragma unroll
  for (int m = 0; m < 24; m++) pw[m] = wred(pw[m]);
#pragma unroll
  for (int o = 0; o < 4; o++){ pm[o] = wred(pm[o]); pb[o] = wred(pb[o]); }
  ph = wred(ph);

#pragma unroll
  for (int o = 0; o < 4; o++) pm[o] += mmb[o];
  float mmx = fmaxf(fmaxf(pm[0], pm[1]), fmaxf(pm[2], pm[3]));
  float msum = 0.f;
#pragma unroll
  for (int o = 0; o < 4; o++){ pm[o] = expf(pm[o] - mmx); msum += pm[o]; }
  float minv = 1.f / msum;
  float gl[10];
#pragma unroll
  for (int e = 0; e < 10; e++){
    float g = ebias[e];
#pragma unroll
    for (int s2 = 0; s2 < 4; s2++) g = fmaf(pm[s2] * minv, ps[s2 * 10 + e] + msb[s2 * 10 + e], g);
    gl[e] = g;
  }
  float gmx = gl[0];
#pragma unroll
  for (int e = 1; e < 10; e++) gmx = fmaxf(gmx, gl[e]);
  float gs = 0.f;
#pragma unroll
  for (int e = 0; e < 10; e++){ gl[e] = expf(gl[e] - gmx); gs += gl[e]; }
  float ginv = 1.f / gs;
#pragma unroll
  for (int e = 0; e < 10; e++) gl[e] *= ginv;
#pragma unroll
  for (int o = 0; o < 4; o++) pb[o] += bb[o];
  int bud = 1; float bbest = pb[0];
  if (pb[1] > bbest){ bbest = pb[1]; bud = 2; }
  if (pb[2] > bbest){ bbest = pb[2]; bud = 3; }
  if (pb[3] > bbest){ bbest = pb[3]; bud = 4; }
  float tv[4]; int ti[4]; unsigned used = 0;
#pragma unroll
  for (int j = 0; j < 4; j++){
    float best = -1e30f; int bi = 0;
#pragma unroll
    for (int e = 0; e < 10; e++){
      bool ok = (!((used >> e) & 1u)) && (gl[e] > best);
      if (ok){ best = gl[e]; bi = e; }
    }
    tv[j] = best; ti[j] = bi; used |= (1u << bi);
  }
  float ssum = tv[0];
  if (bud > 1) ssum += tv[1];
  if (bud > 2) ssum += tv[2];
  if (bud > 3) ssum += tv[3];
  float den = fmaxf(ssum, 1e-6f);
  float sup = 1.f - tv[0] / den;
#pragma unroll
  for (int m = 0; m < 24; m++) pw[m] += wgb[m];
  float wmx = pw[0];
#pragma unroll
  for (int m = 1; m < 24; m++) wmx = fmaxf(wmx, pw[m]);
  float wsum = 0.f;
#pragma unroll
  for (int m = 0; m < 24; m++){ pw[m] = expf(pw[m] - wmx); wsum += pw[m]; }
  float winv = 1.f / wsum;
  float hv = 1.f / (1.f + expf(-(ph + hb[t])));

  if (lane == 0){
#pragma unroll
    for (int e = 0; e < 10; e++){
      float sv = 0.f;
#pragma unroll
      for (int j = 0; j < 4; j++) if (j < bud && ti[j] == e) sv = tv[j] / den;
      sg[row * 10 + e] = sv;
    }
    haltb[row] = hv;
#pragma unroll
    for (int m = 0; m < 24; m++){
      float c = sup * pw[m] * winv;
      float om = 1.f - c;
      Ac[row * 24 + m] *= om;
      if (t > 0) W0[row * 24 + m] *= om;
      if (t > 1) W1[row * 24 + m] *= om;
      if (t > 2) W2[row * 24 + m] *= om;
      if (t == 0)      W0[row * 24 + m] = c;
      else if (t == 1) W1[row * 24 + m] = c;
      else if (t == 2) W2[row * 24 + m] = c;
    }
  }
}

// ---------------- finalize step --------------------------------------------------
__global__ __launch_bounds__(256)
void finalize_kernel(const float* __restrict__ mctx, const float* __restrict__ dctx,
                     const float* __restrict__ mow, const float* __restrict__ dow,
                     const float* __restrict__ EL, const float* __restrict__ haltb,
                     float* __restrict__ total, float* __restrict__ cumh)
{
  int lane = threadIdx.x & 63;
  int row = blockIdx.x * 4 + (threadIdx.x >> 6);
  size_t rb = (size_t)row * IN_D;
  float p1[10], p2[10];
#pragma unroll
  for (int o = 0; o < 10; o++){ p1[o] = 0.f; p2[o] = 0.f; }
  for (int k = lane; k < IN_D; k += 64){
    float mv = mctx[rb + k], dv = dctx[rb + k];
#pragma unroll
    for (int o = 0; o < 10; o++){
      p1[o] = fmaf(mv, mow[o * IN_D + k], p1[o]);
      p2[o] = fmaf(dv, dow[o * IN_D + k], p2[o]);
    }
  }
#pragma unroll
  for (int o = 0; o < 10; o++){ p1[o] = wred(p1[o]); p2[o] = wred(p2[o]); }
  if (lane == 0){
    float rem = 1.f - cumh[row];
#pragma unroll
    for (int o = 0; o < 10; o++)
      total[row * 10 + o] += rem * (EL[row * 10 + o] + 0.22f * p1[o] + 0.14f * p2[o]);
    cumh[row] += rem * haltb[row];
  }
}

// ---------------- base ----------------------------------------------------------
__global__ __launch_bounds__(256)
void base_kernel(const float* __restrict__ x, const float* __restrict__ w,
                 const float* __restrict__ b, float* __restrict__ outp)
{
  int lane = threadIdx.x & 63;
  int row = blockIdx.x * 4 + (threadIdx.x >> 6);
  size_t rb = (size_t)row * IN_D;
  float p[10];
#pragma unroll
  for (int o = 0; o < 10; o++) p[o] = 0.f;
  for (int k = lane; k < IN_D; k += 64){
    float xv = x[rb + k];
#pragma unroll
    for (int o = 0; o < 10; o++) p[o] = fmaf(xv, w[o * IN_D + k], p[o]);
  }
#pragma unroll
  for (int o = 0; o < 10; o++) p[o] = wred(p[o]);
  if (lane == 0){
#pragma unroll
    for (int o = 0; o < 10; o++) outp[row * 10 + o] = p[o] + b[o];
  }
}

// ---------------- shared branch --------------------------------------------------
__global__ __launch_bounds__(256)
void shared_kernel(const float* __restrict__ shpre, const float* __restrict__ sdw,
                   const float* __restrict__ g, const float* __restrict__ b,
                   float* __restrict__ outp)
{
  int lane = threadIdx.x & 63;
  int row = blockIdx.x * 4 + (threadIdx.x >> 6);
  const float* xr = shpre + (size_t)row * SHD;
  float p[10];
#pragma unroll
  for (int o = 0; o < 10; o++) p[o] = 0.f;
  for (int k = lane; k < SHD; k += 64){
    float xv = xr[k];
#pragma unroll
    for (int o = 0; o < 10; o++) p[o] = fmaf(xv, sdw[o * SHD + k], p[o]);
  }
#pragma unroll
  for (int o = 0; o < 10; o++) p[o] = wred(p[o]);
  float mean = 0.f;
#pragma unroll
  for (int o = 0; o < 10; o++) mean += p[o];
  mean *= 0.1f;
  float var = 0.f;
#pragma unroll
  for (int o = 0; o < 10; o++){ float dd = p[o] - mean; var += dd * dd; }
  var *= 0.1f;
  float rs = 1.f / sqrtf(var + 1e-5f);
  if (lane == 0){
#pragma unroll
    for (int o = 0; o < 10; o++) outp[row * 10 + o] = (p[o] - mean) * rs * g[o] + b[o];
  }
}

// ---------------- final output ----------------------------------------------------
__global__ __launch_bounds__(256)
void final_out_kernel(const float* __restrict__ cur, const float* __restrict__ mow,
                      const float* __restrict__ basep, const float* __restrict__ sharedp,
                      const float* __restrict__ total, const float* __restrict__ sscale,
                      const float* __restrict__ alphap, const float* __restrict__ betap,
                      float* __restrict__ outp)
{
  int lane = threadIdx.x & 63;
  int row = blockIdx.x * 4 + (threadIdx.x >> 6);
  size_t rb = (size_t)row * IN_D;
  float p[10];
#pragma unroll
  for (int o = 0; o < 10; o++) p[o] = 0.f;
  for (int k = lane; k < IN_D; k += 64){
    float cv = cur[rb + k];
#pragma unroll
    for (int o = 0; o < 10; o++) p[o] = fmaf(cv, mow[o * IN_D + k], p[o]);
  }
#pragma unroll
  for (int o = 0; o < 10; o++) p[o] = wred(p[o]);
  if (lane == 0){
    float ss = sscale[0], av = alphap[0] + 1e-4f, bv = betap[0];
#pragma unroll
    for (int o = 0; o < 10; o++)
      outp[row * 10 + o] = basep[row * 10 + o] + ss * sharedp[row * 10 + o]
                         + av * (total[row * 10 + o] * 0.25f) + bv * p[o];
  }
}

// ---------------- utility ---------------------------------------------------------
__global__ void cvt_bf16_kernel(const float* __restrict__ src, uint16_t* __restrict__ dst, size_t n){
  size_t i = ((size_t)blockIdx.x * blockDim.x + threadIdx.x) << 2;
  size_t stride = ((size_t)gridDim.x * blockDim.x) << 2;
  for (; i < n; i += stride){
    float4 v = *(const float4*)(src + i);
    ushort4 h;
    h.x = f2bf(v.x); h.y = f2bf(v.y); h.z = f2bf(v.z); h.w = f2bf(v.w);
    *(ushort4*)(dst + i) = h;
  }
}
__global__ void fill1_kernel(float* __restrict__ p, int n){
  int i = blockIdx.x * blockDim.x + threadIdx.x;
  if (i < n) p[i] = 1.f;
}

// ====================================================================================
extern "C" void kernel_launch(void* const* d_in, const int* in_sizes, int n_in,
                              void* d_out, int out_size, void* d_ws, size_t ws_size,
                              hipStream_t stream)
{
  const float* x     = (const float*)d_in[0];
  const float* wgt   = (const float*)d_in[1];
  const float* bias  = (const float*)d_in[2];
  const float* suw   = (const float*)d_in[3];
  const float* sdw   = (const float*)d_in[4];
  const float* sng   = (const float*)d_in[5];
  const float* snb   = (const float*)d_in[6];
  const float* sscale= (const float*)d_in[7];
  const float* keys  = (const float*)d_in[8];
  const float* mvi   = (const float*)d_in[9];
  const float* mqw   = (const float*)d_in[10];
  const float* mow   = (const float*)d_in[11];
  const float* wgw   = (const float*)d_in[12];
  const float* wgb   = (const float*)d_in[13];
  const float* wvw   = (const float*)d_in[14];
  const float* wvb   = (const float*)d_in[15];
  const float* dqw   = (const float*)d_in[16];
  const float* dkw   = (const float*)d_in[17];
  const float* dvw   = (const float*)d_in[18];
  const float* dow   = (const float*)d_in[19];
  const float* clng  = (const float*)d_in[20];
  const float* clnb  = (const float*)d_in[21];
  const float* fc1w  = (const float*)d_in[22];
  const float* fc1b  = (const float*)d_in[23];
  const float* fc2w  = (const float*)d_in[24];
  const float* fc2b  = (const float*)d_in[25];
  const float* saw   = (const float*)d_in[26];
  const float* sab   = (const float*)d_in[27];
  const float* sbw   = (const float*)d_in[28];
  const float* sbb   = (const float*)d_in[29];
  const float* msw   = (const float*)d_in[30];
  const float* msb   = (const float*)d_in[31];
  const float* mmw   = (const float*)d_in[32];
  const float* mmb   = (const float*)d_in[33];
  const float* ebias = (const float*)d_in[34];
  const float* bw    = (const float*)d_in[35];
  const float* bb    = (const float*)d_in[36];
  const float* eup   = (const float*)d_in[37];
  const float* edn   = (const float*)d_in[38];
  const float* eng   = (const float*)d_in[39];
  const float* enb   = (const float*)d_in[40];
  const float* hw    = (const float*)d_in[41];
  const float* hb    = (const float*)d_in[42];
  const float* alphap= (const float*)d_in[43];
  const float* betap = (const float*)d_in[44];
  float* outp = (float*)d_out;

  char* wsb = (char*)d_ws;
  size_t off = 0;
  auto AL = [&](size_t bytes) -> void* {
    void* p = wsb + off;
    off = (off + bytes + 255) & ~(size_t)255;
    return p;
  };
  const size_t NI = (size_t)N_TOK * IN_D;
  float* cur    = (float*)AL(NI * 4);
  float* enr    = (float*)AL(NI * 4);
  float* mqdq   = (float*)AL((size_t)N_TOK * 2048 * 4);
  float* mctx   = (float*)AL(NI * 4);
  float* dctx   = (float*)AL(NI * 4);
  float* t40    = (float*)AL((size_t)N_TOK * 40 * 4);
  float* trio0  = (float*)AL((size_t)N_TOK * 3072 * 4);
  float* trio1  = (float*)AL((size_t)N_TOK * 3072 * 4);
  float* trio2  = (float*)AL((size_t)N_TOK * 3072 * 4);
  float* ubuf   = (float*)AL((size_t)N_TOK * 24 * 4);
  float* sval   = (float*)AL((size_t)N_TOK * 4 * 4);
  float* Ac     = (float*)AL((size_t)N_TOK * 24 * 4);
  float* W0     = (float*)AL((size_t)N_TOK * 24 * 4);
  float* W1     = (float*)AL((size_t)N_TOK * 24 * 4);
  float* W2     = (float*)AL((size_t)N_TOK * 24 * 4);
  float* sg     = (float*)AL((size_t)N_TOK * 10 * 4);
  float* haltb  = (float*)AL((size_t)N_TOK * 4);
  float* EL     = (float*)AL((size_t)N_TOK * 10 * 4);
  float* total  = (float*)AL((size_t)N_TOK * 10 * 4);
  float* cumh   = (float*)AL((size_t)N_TOK * 4);
  float* basep  = (float*)AL((size_t)N_TOK * 10 * 4);
  float* sharedp= (float*)AL((size_t)N_TOK * 10 * 4);
  int*   cnt    = (int*)AL(NEXP * 4);
  int*   gidx   = (int*)AL((size_t)NEXP * N_TOK * 4);
  int*   pos    = (int*)AL((size_t)N_TOK * NEXP * 4);
  float* cbias  = (float*)AL(3072 * 4);
  // bf16 split activations
  uint16_t* curh = (uint16_t*)AL(NI * 2);
  uint16_t* curl = (uint16_t*)AL(NI * 2);
  uint16_t* lnh  = (uint16_t*)AL(NI * 2);
  uint16_t* lnl  = (uint16_t*)AL(NI * 2);
  uint16_t* h7h  = (uint16_t*)AL((size_t)N_TOK * INNER * 2);
  uint16_t* h7l  = (uint16_t*)AL((size_t)N_TOK * INNER * 2);
  // bf16 split weights (fused layouts)
  const size_t W1M = (size_t)IN_D * IN_D;
  uint16_t* mqdqh = (uint16_t*)AL(2 * W1M * 2); uint16_t* mqdql = (uint16_t*)AL(2 * W1M * 2);
  uint16_t* triowh= (uint16_t*)AL(3 * W1M * 2); uint16_t* triowl= (uint16_t*)AL(3 * W1M * 2);
  const size_t WFC = (size_t)NSTEP * INNER * IN_D;
  uint16_t* fc1wh = (uint16_t*)AL(WFC * 2); uint16_t* fc1wl = (uint16_t*)AL(WFC * 2);
  uint16_t* fc2wh = (uint16_t*)AL(WFC * 2); uint16_t* fc2wl = (uint16_t*)AL(WFC * 2);
  const size_t WSU = (size_t)SHD * IN_D;
  uint16_t* suwh = (uint16_t*)AL(WSU * 2); uint16_t* suwl = (uint16_t*)AL(WSU * 2);
  // big buffers
  uint16_t* upbf  = (uint16_t*)AL((size_t)NEXP * DMAX * IN_D * 2);
  uint16_t* HHc   = (uint16_t*)AL((size_t)N_TOK * DSUM * 2);
  float* shpre  = (float*)HHc;   // alias: consumed before HHc is written

  // ---- init ----
  hipMemsetAsync(dctx, 0, NI * 4, stream);
  hipMemsetAsync(total, 0, (size_t)N_TOK * 10 * 4, stream);
  hipMemsetAsync(cumh, 0, (size_t)N_TOK * 4, stream);
  hipMemsetAsync(cbias, 0, 3072 * 4, stream);
  hipMemcpyAsync(cbias + 2048, wvb, 1024 * 4, hipMemcpyDeviceToDevice, stream);
  hipMemcpyAsync(cur, x, NI * 4, hipMemcpyDeviceToDevice, stream);
  fill1_kernel<<<(N_TOK * 24 + 255) / 256, 256, 0, stream>>>(Ac, N_TOK * 24);
  cvt_bf16_kernel<<<2048, 256, 0, stream>>>(eup, upbf, (size_t)NEXP * DMAX * IN_D);
  // weight splits into fused layouts
  split_kernel<<<1024, 256, 0, stream>>>(mqw, mqdqh, mqdql, W1M);
  split_kernel<<<1024, 256, 0, stream>>>(dqw, mqdqh + W1M, mqdql + W1M, W1M);
  split_kernel<<<1024, 256, 0, stream>>>(dkw, triowh, triowl, W1M);
  split_kernel<<<1024, 256, 0, stream>>>(dvw, triowh + W1M, triowl + W1M, W1M);
  split_kernel<<<1024, 256, 0, stream>>>(wvw, triowh + 2*W1M, triowl + 2*W1M, W1M);
  split_kernel<<<1024, 256, 0, stream>>>(fc1w, fc1wh, fc1wl, WFC);
  split_kernel<<<1024, 256, 0, stream>>>(fc2w, fc2wh, fc2wl, WFC);
  split_kernel<<<1024, 256, 0, stream>>>(suw, suwh, suwl, WSU);
  split_kernel<<<1024, 256, 0, stream>>>(x, curh, curl, NI);

  base_kernel<<<512, 256, 0, stream>>>(x, wgt, bias, basep);
  gemm_sp<EPI_SILU><<<dim3(SHD/128, N_TOK/128), 256, 0, stream>>>(
      curh, curl, suwh, suwl, nullptr, nullptr, shpre, nullptr, nullptr, IN_D, SHD);
  shared_kernel<<<512, 256, 0, stream>>>(shpre, sdw, sng, snb, sharedp);

  float* trioB[3] = {trio0, trio1, trio2};

  for (int t = 0; t < NSTEP; t++){
    // fused q-projections: cols [0,1024)=mq, [1024,2048)=dq (dq only needed t>0)
    gemm_sp<EPI_NONE><<<dim3(t > 0 ? 16 : 8, 16), 256, 0, stream>>>(
        curh, curl, mqdqh, mqdql, nullptr, nullptr, mqdq, nullptr, nullptr, IN_D, 2048);
    mem_attn_kernel<<<512, 256, 0, stream>>>(mqdq, 2048, keys, Ac, W0, W1, W2, ubuf, sval, t);
    mem_ctx_kernel<<<2048, 256, 0, stream>>>(ubuf, mvi, sval, trio0, trio1, trio2, mctx, t);
    if (t > 0)
      depth_kernel<<<512, 256, 0, stream>>>(mqdq + 1024, 2048, trio0, trio1, trio2, dctx, t);
    ssm_a_kernel<<<512, 256, 0, stream>>>(cur, saw, sab, t40);
    enriched_kernel<<<2048, 256, 0, stream>>>(cur, mctx, dctx, t40, sbw, sbb, clng, clnb,
                                              enr, lnh, lnl, t);
    // cell MLP (bf16 splits fused into epilogues)
    gemm_sp<EPI_GELU_BIAS><<<dim3(INNER/128, 16), 256, 0, stream>>>(
        lnh, lnl, fc1wh + (size_t)t * INNER * IN_D, fc1wl + (size_t)t * INNER * IN_D,
        fc1b + t * INNER, nullptr, nullptr, h7h, h7l, IN_D, INNER);
    gemm_sp<EPI_ADD_BIAS><<<dim3(8, 16), 256, 0, stream>>>(
        h7h, h7l, fc2wh + (size_t)t * IN_D * INNER, fc2wl + (size_t)t * IN_D * INNER,
        fc2b + t * IN_D, enr, cur, curh, curl, INNER, IN_D);
    // fused bank projections: cols [0,1024)=k, [1024,2048)=v, [2048,3072)=wv
    if (t < 3)
      gemm_sp<EPI_BIAS><<<dim3(24, 16), 256, 0, stream>>>(
          curh, curl, triowh, triowl, cbias, nullptr, trioB[t], nullptr, nullptr, IN_D, 3072);
    // routing + compaction
    routing_kernel<<<512, 256, 0, stream>>>(cur, mctx, dctx, msw, msb, mmw, mmb, ebias,
                                            bw, bb, wgw, wgb, hw, hb,
                                            sg, haltb, Ac, W0, W1, W2, t);
    hipMemsetAsync(cnt, 0, NEXP * 4, stream);
    compact_kernel<<<N_TOK / 256, 256, 0, stream>>>(sg, cnt, gidx, pos);
    // sparse experts
    expert_up_mfma<<<dim3(16, 26, 10), 256, 0, stream>>>(curh, upbf, cnt, gidx, HHc);
    expert_down<<<512, 256, 0, stream>>>(HHc, pos, edn, sg, eng, enb, EL);
    finalize_kernel<<<512, 256, 0, stream>>>(mctx, dctx, mow, dow, EL, haltb, total, cumh);
  }
  final_out_kernel<<<512, 256, 0, stream>>>(cur, mow, basep, sharedp, total, sscale,
                                            alphap, betap, outp);
}